// Round 3
// baseline (544.637 us; speedup 1.0000x reference)
//
#include <hip/hip_runtime.h>
#include <hip/hip_bf16.h>
#include <math.h>

// ---------- types ----------
typedef __attribute__((ext_vector_type(8))) short bf16x8;
typedef __attribute__((ext_vector_type(4))) float f32x4;

#define MFMA16(a, b, c) __builtin_amdgcn_mfma_f32_16x16x32_bf16((a), (b), (c), 0, 0, 0)

static __device__ __forceinline__ unsigned short f2bf(float f) {
  __hip_bfloat16 h = __float2bfloat16(f);
  unsigned short u;
  __builtin_memcpy(&u, &h, 2);
  return u;
}
static __device__ __forceinline__ float bf2f(unsigned short u) {
  unsigned int x = ((unsigned int)u) << 16;
  float f;
  __builtin_memcpy(&f, &x, 4);
  return f;
}

// ---------- cast fp32 -> bf16 (vectorized) ----------
__global__ void cast_f32_bf16(const float* __restrict__ src, unsigned short* __restrict__ dst, int n) {
  int i = (blockIdx.x * 256 + threadIdx.x) * 8;
  if (i >= n) return;
  float4 a = *(const float4*)(src + i);
  float4 b = *(const float4*)(src + i + 4);
  union { unsigned short u[8]; bf16x8 v; } o;
  o.u[0] = f2bf(a.x); o.u[1] = f2bf(a.y); o.u[2] = f2bf(a.z); o.u[3] = f2bf(a.w);
  o.u[4] = f2bf(b.x); o.u[5] = f2bf(b.y); o.u[6] = f2bf(b.z); o.u[7] = f2bf(b.w);
  *(bf16x8*)(dst + i) = o.v;
}

// ---------- Wsmall = [Wkv(256) ; Wkvh(32) ; zeros(96)]  (384 x 2048, bf16) ----------
__global__ void build_wsmall(const float* __restrict__ Wkv, const float* __restrict__ Wkvh,
                             unsigned short* __restrict__ dst) {
  int row = blockIdx.x;
  int c = threadIdx.x * 8;
  const float* src = nullptr;
  if (row < 256) src = Wkv + (size_t)row * 2048;
  else if (row < 288) src = Wkvh + (size_t)(row - 256) * 2048;
  union { unsigned short u[8]; bf16x8 v; } o;
  if (src) {
    float4 a = *(const float4*)(src + c);
    float4 b = *(const float4*)(src + c + 4);
    o.u[0] = f2bf(a.x); o.u[1] = f2bf(a.y); o.u[2] = f2bf(a.z); o.u[3] = f2bf(a.w);
    o.u[4] = f2bf(b.x); o.u[5] = f2bf(b.y); o.u[6] = f2bf(b.z); o.u[7] = f2bf(b.w);
  } else {
    for (int j = 0; j < 8; j++) o.u[j] = 0;
  }
  *(bf16x8*)(dst + (size_t)row * 2048 + c) = o.v;
}

// ---------- rope cos/sin table ----------
__global__ void rope_table(float2* __restrict__ cs) {
  int i = blockIdx.x * 256 + threadIdx.x;
  int f = i & 63, n = i >> 6;
  float inv = powf(10000.0f, -(float)(2 * f) / 128.0f);
  float ang = (float)n * inv;
  cs[i] = make_float2(cosf(ang), sinf(ang));
}

// ---------- Wgt[k][oc] <- Wg[oc][k]  (32 x 2048 fp32) ----------
__global__ void transpose_wg(const float* __restrict__ Wg, float* __restrict__ Wgt) {
  int i = blockIdx.x * 256 + threadIdx.x;  // 65536
  int oc = i >> 11, k = i & 2047;
  Wgt[(size_t)k * 32 + oc] = Wg[i];
}

// ---------- g = x @ Wg^T in fp32 (Wgt coalesced) ----------
__global__ __launch_bounds__(256) void gproj(const float* __restrict__ x, const float* __restrict__ Wgt,
                                             float* __restrict__ g) {
  int tid = blockIdx.x * 256 + threadIdx.x;  // 4096*32
  int tok = tid >> 5, oc = tid & 31;
  const float* xr = x + (size_t)tok * 2048;
  float acc = 0.f;
  for (int k = 0; k < 2048; k += 4) {
    float4 a = *(const float4*)(xr + k);
    acc += a.x * Wgt[(size_t)k * 32 + oc] + a.y * Wgt[(size_t)(k + 1) * 32 + oc] +
           a.z * Wgt[(size_t)(k + 2) * 32 + oc] + a.w * Wgt[(size_t)(k + 3) * 32 + oc];
  }
  g[(size_t)tok * 32 + oc] = acc;
}

// ---------- gated double cumsum scan: 1 block per batch, 32 segs x 32 ch ----------
__global__ __launch_bounds__(1024) void scan_kernel(const float* __restrict__ g,
                                                    const float* __restrict__ small_out,
                                                    float* __restrict__ khvh) {
  int b = blockIdx.x;
  int t = threadIdx.x;
  int ch = t & 31, seg = t >> 5;  // 32 segs x 64 toks
  int base = b * 2048 + seg * 64;
  __shared__ float part[1024];
  float lsg[64];
  float run = 0.f;
#pragma unroll
  for (int j = 0; j < 64; j++) {
    float gv = g[(size_t)(base + j) * 32 + ch];
    float ls = (gv >= 0.f) ? -log1pf(expf(-gv)) : gv - log1pf(expf(gv));
    run += ls;
    lsg[j] = run;
  }
  part[seg * 32 + ch] = run;
  __syncthreads();
  for (int off = 1; off < 32; off <<= 1) {
    float v = (seg >= off) ? part[(seg - off) * 32 + ch] : 0.f;
    __syncthreads();
    part[seg * 32 + ch] += v;
    __syncthreads();
  }
  float baseA = (seg > 0) ? part[(seg - 1) * 32 + ch] : 0.f;
  __syncthreads();
  float run2 = 0.f;
#pragma unroll
  for (int j = 0; j < 64; j++) {
    float kvh = small_out[(size_t)(base + j) * 384 + 256 + ch];
    float lf = baseA + (j > 0 ? lsg[j - 1] : 0.f);
    run2 += kvh * expf(lf);
  }
  part[seg * 32 + ch] = run2;
  __syncthreads();
  for (int off = 1; off < 32; off <<= 1) {
    float v = (seg >= off) ? part[(seg - off) * 32 + ch] : 0.f;
    __syncthreads();
    part[seg * 32 + ch] += v;
    __syncthreads();
  }
  float run3 = (seg > 0) ? part[(seg - 1) * 32 + ch] : 0.f;
#pragma unroll
  for (int j = 0; j < 64; j++) {
    float kvh = small_out[(size_t)(base + j) * 384 + 256 + ch];
    float lf = baseA + (j > 0 ? lsg[j - 1] : 0.f);
    run3 += kvh * expf(lf);
    khvh[(size_t)(base + j) * 32 + ch] = run3;
  }
}

// ---------- rope q in place (vectorized) ----------
__global__ void rope_q(unsigned short* __restrict__ q_r, const float2* __restrict__ cs) {
  int i = blockIdx.x * 256 + threadIdx.x;  // 32*2048*8
  int fc = (i & 7) * 8;
  int n = (i >> 3) & 2047;
  int bh = i >> 14;
  unsigned short* p = q_r + ((size_t)bh * 2048 + n) * 128;
  union { unsigned short u[8]; bf16x8 v; } a, b, oa, ob;
  a.v = *(bf16x8*)(p + fc);
  b.v = *(bf16x8*)(p + 64 + fc);
#pragma unroll
  for (int j = 0; j < 8; j++) {
    float t1 = bf2f(a.u[j]), t2 = bf2f(b.u[j]);
    float2 c = cs[(n << 6) + fc + j];
    oa.u[j] = f2bf(t1 * c.x - t2 * c.y);
    ob.u[j] = f2bf(t2 * c.x + t1 * c.y);
  }
  *(bf16x8*)(p + fc) = oa.v;
  *(bf16x8*)(p + 64 + fc) = ob.v;
}

// ---------- build k_r, v_r (vectorized stores) ----------
__global__ __launch_bounds__(256) void build_kv(const float* __restrict__ small_out,
                                                const float* __restrict__ khvh,
                                                const float2* __restrict__ cs,
                                                unsigned short* __restrict__ k_r,
                                                unsigned short* __restrict__ v_r) {
  int tok = blockIdx.x;
  int b = tok >> 11, n = tok & 2047;
  __shared__ float kpr[128], vps[128], khs[16], vhs[16];
  int t = threadIdx.x;
  const float* so = small_out + (size_t)tok * 384;
  if (t < 64) {
    float k1 = so[t], k2 = so[t + 64];
    float2 c = cs[(n << 6) + t];
    kpr[t] = k1 * c.x - k2 * c.y;
    kpr[t + 64] = k2 * c.x + k1 * c.y;
  } else if (t < 192) {
    int d = t - 64;
    vps[d] = so[128 + d];
  } else if (t < 224) {
    int ch = t - 192;
    float v = khvh[(size_t)tok * 32 + ch];
    if (ch < 16) khs[ch] = v; else vhs[ch - 16] = v;
  }
  __syncthreads();
  int h = t >> 4, d0 = (t & 15) * 8;
  float kh = khs[h], vh = vhs[h];
  union { unsigned short u[8]; bf16x8 v; } ko, vo;
#pragma unroll
  for (int j = 0; j < 8; j++) {
    ko.u[j] = f2bf(kpr[d0 + j] * kh);
    vo.u[j] = f2bf(vps[d0 + j] * vh);
  }
  size_t off = (((size_t)b * 16 + h) * 2048 + n) * 128 + d0;
  *(bf16x8*)(k_r + off) = ko.v;
  *(bf16x8*)(v_r + off) = vo.v;
}

// ---------- v_t (b,h,d,n) <- v_r (b,h,n,d) ----------
__global__ __launch_bounds__(256) void transpose_v(const unsigned short* __restrict__ v_r,
                                                   unsigned short* __restrict__ v_t) {
  int nt = blockIdx.x;
  int bh = blockIdx.y;
  __shared__ unsigned short Ts[64 * 136];
  int tid = threadIdx.x;
  const unsigned short* src = v_r + ((size_t)bh * 2048 + nt * 64) * 128;
#pragma unroll
  for (int c = 0; c < 4; c++) {
    int g = c * 256 + tid;
    int r = g >> 4, ch = (g & 15) * 8;
    *(bf16x8*)&Ts[r * 136 + ch] = *(const bf16x8*)(src + r * 128 + ch);
  }
  __syncthreads();
#pragma unroll
  for (int c = 0; c < 4; c++) {
    int g = c * 256 + tid;
    int d = g >> 3, nc = (g & 7) * 8;
    union { unsigned short u[8]; bf16x8 v; } o;
#pragma unroll
    for (int j = 0; j < 8; j++) o.u[j] = Ts[(nc + j) * 136 + d];
    *(bf16x8*)(v_t + ((size_t)bh * 128 + d) * 2048 + nt * 64 + nc) = o.v;
  }
}

// ---------- m97-style NT GEMM ----------
template <int MODE>
__global__ __launch_bounds__(256) void gemm_bt(const unsigned short* __restrict__ A,
                                               const unsigned short* __restrict__ B,
                                               float* __restrict__ Cf,
                                               unsigned short* __restrict__ Cb,
                                               int K, int ldc) {
  __shared__ unsigned short As[128 * 32];
  __shared__ unsigned short Bs[128 * 32];
  int tid = threadIdx.x;
  int wave = tid >> 6, lane = tid & 63, l15 = lane & 15, lg = lane >> 4;
  int wr = wave >> 1, wc = wave & 1;
  int row0 = blockIdx.y * 128, col0 = blockIdx.x * 128;
  f32x4 acc[4][4];
#pragma unroll
  for (int m = 0; m < 4; m++)
#pragma unroll
    for (int n = 0; n < 4; n++) acc[m][n] = (f32x4){0.f, 0.f, 0.f, 0.f};

  for (int k0 = 0; k0 < K; k0 += 32) {
#pragma unroll
    for (int c = 0; c < 2; c++) {
      int chunk = c * 256 + tid;
      int r = chunk >> 2, kk = (chunk & 3) * 8;
      __builtin_amdgcn_global_load_lds(
          (const __attribute__((address_space(1))) void*)(A + (size_t)(row0 + r) * K + k0 + kk),
          (__attribute__((address_space(3))) void*)(As + ((size_t)c * 256 + wave * 64) * 8), 16, 0, 0);
      __builtin_amdgcn_global_load_lds(
          (const __attribute__((address_space(1))) void*)(B + (size_t)(col0 + r) * K + k0 + kk),
          (__attribute__((address_space(3))) void*)(Bs + ((size_t)c * 256 + wave * 64) * 8), 16, 0, 0);
    }
    __syncthreads();
    bf16x8 af[4], bfr[4];
#pragma unroll
    for (int m = 0; m < 4; m++) af[m] = *(const bf16x8*)&As[(wr * 64 + m * 16 + l15) * 32 + lg * 8];
#pragma unroll
    for (int n = 0; n < 4; n++) bfr[n] = *(const bf16x8*)&Bs[(wc * 64 + n * 16 + l15) * 32 + lg * 8];
#pragma unroll
    for (int m = 0; m < 4; m++)
#pragma unroll
      for (int n = 0; n < 4; n++) acc[m][n] = MFMA16(af[m], bfr[n], acc[m][n]);
    __syncthreads();
  }
#pragma unroll
  for (int m = 0; m < 4; m++) {
    int row_b = row0 + wr * 64 + m * 16 + lg * 4;
#pragma unroll
    for (int n = 0; n < 4; n++) {
      int col = col0 + wc * 64 + n * 16 + l15;
#pragma unroll
      for (int j = 0; j < 4; j++) {
        int row = row_b + j;
        if (MODE == 0) {
          Cf[(size_t)row * ldc + col] = acc[m][n][j];
        } else {
          int b = row >> 11, nn = row & 2047, h = col >> 7, d = col & 127;
          Cb[(((size_t)b * 16 + h) * 2048 + nn) * 128 + d] = f2bf(acc[m][n][j]);
        }
      }
    }
  }
}

// ---------- flash attention v3: two Q-tiles per block (balanced 33 steps), dbuf staging ----------
__global__ __launch_bounds__(256, 2) void flash_attn(const unsigned short* __restrict__ q_r,
                                                     const unsigned short* __restrict__ k_r,
                                                     const unsigned short* __restrict__ v_t,
                                                     unsigned short* __restrict__ o) {
  int bx = blockIdx.x, bh = blockIdx.y;
  const unsigned short* Kg = k_r + (size_t)bh * 2048 * 128;
  const unsigned short* Vtg = v_t + (size_t)bh * 128 * 2048;
  __shared__ unsigned short Ks[2][64 * 128];
  __shared__ unsigned short VTs[2][128 * 64];
  __shared__ unsigned short Ps[4][16 * 72];
  int tid = threadIdx.x, wave = tid >> 6, lane = tid & 63, l15 = lane & 15, lg = lane >> 4;
  int sw = (l15 & 7) * 8;
  int b = bh >> 4, h = bh & 15;

  int qtA = bx, qtB = 31 - bx;
  int qt = qtA;
  const unsigned short* Qg = q_r + ((size_t)bh * 2048 + qt * 64) * 128;
  bf16x8 qf[4];
#pragma unroll
  for (int kk = 0; kk < 4; kk++)
    qf[kk] = *(const bf16x8*)(Qg + (wave * 16 + l15) * 128 + kk * 32 + lg * 8);

  float m_r[4], l_r[4];
  f32x4 oacc[8];
#pragma unroll
  for (int j = 0; j < 4; j++) { m_r[j] = -INFINITY; l_r[j] = 0.f; }
#pragma unroll
  for (int db = 0; db < 8; db++) oacc[db] = (f32x4){0.f, 0.f, 0.f, 0.f};

  const float scale = 0.08838834764831845f;  // 1/sqrt(128)

  // stage kv tile kt into buffer bsel
#define STAGE(kt, bsel)                                                                           \
  {                                                                                               \
    int kti = (kt);                                                                               \
    int bs = (bsel);                                                                              \
    _Pragma("unroll") for (int c = 0; c < 4; c++) {                                               \
      int s = c * 256 + tid;                                                                      \
      int kr = s >> 4, kc = ((s & 15) ^ (kr & 7)) * 8;                                            \
      __builtin_amdgcn_global_load_lds(                                                           \
          (const __attribute__((address_space(1))) void*)(Kg + (size_t)(kti * 64 + kr) * 128 + kc),\
          (__attribute__((address_space(3))) void*)(&Ks[bs][(c * 256 + wave * 64) * 8]), 16, 0, 0);\
      int vr = s >> 3, vc = ((s & 7) ^ (vr & 7)) * 8;                                             \
      __builtin_amdgcn_global_load_lds(                                                           \
          (const __attribute__((address_space(1))) void*)(Vtg + (size_t)vr * 2048 + kti * 64 + vc),\
          (__attribute__((address_space(3))) void*)(&VTs[bs][(c * 256 + wave * 64) * 8]), 16, 0, 0);\
    }                                                                                             \
  }

  STAGE(0, 0);
  __syncthreads();

  for (int s = 0; s < 33; ++s) {
    int nb = s & 1;
    if (s + 1 < 33) {
      int nk = (s + 1 <= qtA) ? (s + 1) : (s + 1 - (qtA + 1));
      STAGE(nk, nb ^ 1);
    }
    int kt = (s <= qtA) ? s : (s - (qtA + 1));
    bool diag = (s == qtA) || (s == 32);
    int qrow0 = qt * 64 + wave * 16 + lg * 4;

    f32x4 sc[4];
#pragma unroll
    for (int cb = 0; cb < 4; cb++) sc[cb] = (f32x4){0.f, 0.f, 0.f, 0.f};
#pragma unroll
    for (int kk = 0; kk < 4; kk++) {
#pragma unroll
      for (int cb = 0; cb < 4; cb++) {
        bf16x8 kf = *(const bf16x8*)&Ks[nb][(cb * 16 + l15) * 128 + ((kk * 32 + lg * 8) ^ sw)];
        sc[cb] = MFMA16(qf[kk], kf, sc[cb]);
      }
    }
    float pm[4] = {-INFINITY, -INFINITY, -INFINITY, -INFINITY};
    if (diag) {
#pragma unroll
      for (int cb = 0; cb < 4; cb++) {
        int col = kt * 64 + cb * 16 + l15;
#pragma unroll
        for (int j = 0; j < 4; j++) {
          float v = sc[cb][j] * scale;
          if (col > qrow0 + j) v = -INFINITY;
          sc[cb][j] = v;
          pm[j] = fmaxf(pm[j], v);
        }
      }
    } else {
#pragma unroll
      for (int cb = 0; cb < 4; cb++)
#pragma unroll
        for (int j = 0; j < 4; j++) {
          float v = sc[cb][j] * scale;
          sc[cb][j] = v;
          pm[j] = fmaxf(pm[j], v);
        }
    }
#pragma unroll
    for (int off = 1; off < 16; off <<= 1) {
#pragma unroll
      for (int j = 0; j < 4; j++) pm[j] = fmaxf(pm[j], __shfl_xor(pm[j], off));
    }
    float corr[4], rs[4];
#pragma unroll
    for (int j = 0; j < 4; j++) {
      float mn = fmaxf(m_r[j], pm[j]);
      corr[j] = __expf(m_r[j] - mn);
      m_r[j] = mn;
      rs[j] = 0.f;
    }
    float p[4][4];
#pragma unroll
    for (int cb = 0; cb < 4; cb++)
#pragma unroll
      for (int j = 0; j < 4; j++) {
        float pv = __expf(sc[cb][j] - m_r[j]);
        p[cb][j] = pv;
        rs[j] += pv;
      }
#pragma unroll
    for (int off = 1; off < 16; off <<= 1) {
#pragma unroll
      for (int j = 0; j < 4; j++) rs[j] += __shfl_xor(rs[j], off);
    }
#pragma unroll
    for (int j = 0; j < 4; j++) l_r[j] = l_r[j] * corr[j] + rs[j];
#pragma unroll
    for (int db = 0; db < 8; db++) {
      f32x4 t = oacc[db];
#pragma unroll
      for (int j = 0; j < 4; j++) t[j] *= corr[j];
      oacc[db] = t;
    }
#pragma unroll
    for (int cb = 0; cb < 4; cb++)
#pragma unroll
      for (int j = 0; j < 4; j++) Ps[wave][(lg * 4 + j) * 72 + cb * 16 + l15] = f2bf(p[cb][j]);
#pragma unroll
    for (int kc = 0; kc < 2; kc++) {
      bf16x8 pa = *(const bf16x8*)&Ps[wave][l15 * 72 + kc * 32 + lg * 8];
#pragma unroll
      for (int db = 0; db < 8; db++) {
        bf16x8 vb = *(const bf16x8*)&VTs[nb][(db * 16 + l15) * 64 + ((kc * 32 + lg * 8) ^ sw)];
        oacc[db] = MFMA16(pa, vb, oacc[db]);
      }
    }
    __syncthreads();

    if (s == qtA) {
      // epilogue tile A, then switch to tile B
      int qrow_e = qt * 64 + wave * 16 + lg * 4;
#pragma unroll
      for (int db = 0; db < 8; db++) {
        int d = db * 16 + l15;
#pragma unroll
        for (int j = 0; j < 4; j++) {
          float val = oacc[db][j] / l_r[j];
          o[((size_t)(b * 2048 + qrow_e + j)) * 2048 + h * 128 + d] = f2bf(val);
        }
      }
      qt = qtB;
      Qg = q_r + ((size_t)bh * 2048 + qt * 64) * 128;
#pragma unroll
      for (int kk = 0; kk < 4; kk++)
        qf[kk] = *(const bf16x8*)(Qg + (wave * 16 + l15) * 128 + kk * 32 + lg * 8);
#pragma unroll
      for (int j = 0; j < 4; j++) { m_r[j] = -INFINITY; l_r[j] = 0.f; }
#pragma unroll
      for (int db = 0; db < 8; db++) oacc[db] = (f32x4){0.f, 0.f, 0.f, 0.f};
    }
  }
  // epilogue tile B
  int qrow_e = qt * 64 + wave * 16 + lg * 4;
#pragma unroll
  for (int db = 0; db < 8; db++) {
    int d = db * 16 + l15;
#pragma unroll
    for (int j = 0; j < 4; j++) {
      float val = oacc[db][j] / l_r[j];
      o[((size_t)(b * 2048 + qrow_e + j)) * 2048 + h * 128 + d] = f2bf(val);
    }
  }
#undef STAGE
}

// ---------- host launch ----------
extern "C" void kernel_launch(void* const* d_in, const int* in_sizes, int n_in,
                              void* d_out, int out_size, void* d_ws, size_t ws_size,
                              hipStream_t stream) {
  (void)in_sizes; (void)n_in; (void)out_size; (void)ws_size;
  const float* x    = (const float*)d_in[0];
  const float* Wq   = (const float*)d_in[1];
  const float* Wkv  = (const float*)d_in[2];
  const float* Wkvh = (const float*)d_in[3];
  const float* Wg   = (const float*)d_in[4];
  const float* Wout = (const float*)d_in[5];
  float* out = (float*)d_out;

  char* ws = (char*)d_ws;
  size_t off = 0;
  auto alloc = [&](size_t bytes) -> void* {
    void* p = ws + off;
    off += (bytes + 255) & ~(size_t)255;
    return p;
  };
  unsigned short* x_bf    = (unsigned short*)alloc(4096ull * 2048 * 2);
  unsigned short* wq_bf   = (unsigned short*)alloc(2048ull * 2048 * 2);
  unsigned short* wout_bf = (unsigned short*)alloc(2048ull * 2048 * 2);
  unsigned short* wsm_bf  = (unsigned short*)alloc(384ull * 2048 * 2);
  unsigned short* q_r     = (unsigned short*)alloc(4096ull * 2048 * 2);
  unsigned short* k_r     = (unsigned short*)alloc(4096ull * 2048 * 2);
  unsigned short* v_r     = (unsigned short*)alloc(4096ull * 2048 * 2);
  unsigned short* o_bf    = (unsigned short*)alloc(4096ull * 2048 * 2);
  float* small_out        = (float*)alloc(4096ull * 384 * 4);
  float* g_f              = (float*)alloc(4096ull * 32 * 4);
  float* khvh             = (float*)alloc(4096ull * 32 * 4);
  float2* cs              = (float2*)alloc(2048ull * 64 * 8);
  float* wgt              = (float*)alloc(2048ull * 32 * 4);
  // v_t aliases x_bf: x_bf is dead after the q/small GEMMs
  unsigned short* v_t     = x_bf;

  cast_f32_bf16<<<4096, 256, 0, stream>>>(x, x_bf, 4096 * 2048);
  cast_f32_bf16<<<2048, 256, 0, stream>>>(Wq, wq_bf, 2048 * 2048);
  cast_f32_bf16<<<2048, 256, 0, stream>>>(Wout, wout_bf, 2048 * 2048);
  build_wsmall<<<384, 256, 0, stream>>>(Wkv, Wkvh, wsm_bf);
  rope_table<<<512, 256, 0, stream>>>(cs);
  transpose_wg<<<256, 256, 0, stream>>>(Wg, wgt);
  gproj<<<512, 256, 0, stream>>>(x, wgt, g_f);
  gemm_bt<0><<<dim3(3, 32), 256, 0, stream>>>(x_bf, wsm_bf, small_out, nullptr, 2048, 384);
  gemm_bt<2><<<dim3(16, 32), 256, 0, stream>>>(x_bf, wq_bf, nullptr, q_r, 2048, 2048);
  scan_kernel<<<2, 1024, 0, stream>>>(g_f, small_out, khvh);
  rope_q<<<2048, 256, 0, stream>>>(q_r, cs);
  build_kv<<<4096, 256, 0, stream>>>(small_out, khvh, cs, k_r, v_r);
  transpose_v<<<dim3(32, 32), 256, 0, stream>>>(v_r, v_t);
  flash_attn<<<dim3(16, 32), 256, 0, stream>>>(q_r, k_r, v_t, o_bf);
  gemm_bt<0><<<dim3(16, 32), 256, 0, stream>>>(o_bf, wout_bf, out, nullptr, 2048, 2048);
}

// Round 4
// 355.002 us; speedup vs baseline: 1.5342x; 1.5342x over previous
//
#include <hip/hip_runtime.h>
#include <hip/hip_bf16.h>
#include <math.h>

// ---------- types ----------
typedef __attribute__((ext_vector_type(8))) short bf16x8;
typedef __attribute__((ext_vector_type(4))) float f32x4;

#define MFMA16(a, b, c) __builtin_amdgcn_mfma_f32_16x16x32_bf16((a), (b), (c), 0, 0, 0)

static __device__ __forceinline__ unsigned short f2bf(float f) {
  __hip_bfloat16 h = __float2bfloat16(f);
  unsigned short u;
  __builtin_memcpy(&u, &h, 2);
  return u;
}
static __device__ __forceinline__ float bf2f(unsigned short u) {
  unsigned int x = ((unsigned int)u) << 16;
  float f;
  __builtin_memcpy(&f, &x, 4);
  return f;
}

// ---------- cast fp32 -> bf16 (vectorized) ----------
__global__ void cast_f32_bf16(const float* __restrict__ src, unsigned short* __restrict__ dst, int n) {
  int i = (blockIdx.x * 256 + threadIdx.x) * 8;
  if (i >= n) return;
  float4 a = *(const float4*)(src + i);
  float4 b = *(const float4*)(src + i + 4);
  union { unsigned short u[8]; bf16x8 v; } o;
  o.u[0] = f2bf(a.x); o.u[1] = f2bf(a.y); o.u[2] = f2bf(a.z); o.u[3] = f2bf(a.w);
  o.u[4] = f2bf(b.x); o.u[5] = f2bf(b.y); o.u[6] = f2bf(b.z); o.u[7] = f2bf(b.w);
  *(bf16x8*)(dst + i) = o.v;
}

// ---------- Wsmall = [Wkv(256) ; Wkvh(32) ; zeros(96)]  (384 x 2048, bf16) ----------
__global__ void build_wsmall(const float* __restrict__ Wkv, const float* __restrict__ Wkvh,
                             unsigned short* __restrict__ dst) {
  int row = blockIdx.x;
  int c = threadIdx.x * 8;
  const float* src = nullptr;
  if (row < 256) src = Wkv + (size_t)row * 2048;
  else if (row < 288) src = Wkvh + (size_t)(row - 256) * 2048;
  union { unsigned short u[8]; bf16x8 v; } o;
  if (src) {
    float4 a = *(const float4*)(src + c);
    float4 b = *(const float4*)(src + c + 4);
    o.u[0] = f2bf(a.x); o.u[1] = f2bf(a.y); o.u[2] = f2bf(a.z); o.u[3] = f2bf(a.w);
    o.u[4] = f2bf(b.x); o.u[5] = f2bf(b.y); o.u[6] = f2bf(b.z); o.u[7] = f2bf(b.w);
  } else {
    for (int j = 0; j < 8; j++) o.u[j] = 0;
  }
  *(bf16x8*)(dst + (size_t)row * 2048 + c) = o.v;
}

// ---------- rope cos/sin table ----------
__global__ void rope_table(float2* __restrict__ cs) {
  int i = blockIdx.x * 256 + threadIdx.x;
  int f = i & 63, n = i >> 6;
  float inv = powf(10000.0f, -(float)(2 * f) / 128.0f);
  float ang = (float)n * inv;
  cs[i] = make_float2(cosf(ang), sinf(ang));
}

// ---------- Wgt[k][oc] <- Wg[oc][k]  (32 x 2048 fp32) ----------
__global__ void transpose_wg(const float* __restrict__ Wg, float* __restrict__ Wgt) {
  int i = blockIdx.x * 256 + threadIdx.x;  // 65536
  int oc = i >> 11, k = i & 2047;
  Wgt[(size_t)k * 32 + oc] = Wg[i];
}

// ---------- lsg_t[b][ch][n] = log_sigmoid(x @ Wg^T), transposed write ----------
__global__ __launch_bounds__(256) void gproj(const float* __restrict__ x, const float* __restrict__ Wgt,
                                             float* __restrict__ lsg_t) {
  int tid = blockIdx.x * 256 + threadIdx.x;  // 4096*32
  int tok = tid >> 5, oc = tid & 31;
  const float* xr = x + (size_t)tok * 2048;
  float acc = 0.f;
  for (int k = 0; k < 2048; k += 4) {
    float4 a = *(const float4*)(xr + k);
    acc += a.x * Wgt[(size_t)k * 32 + oc] + a.y * Wgt[(size_t)(k + 1) * 32 + oc] +
           a.z * Wgt[(size_t)(k + 2) * 32 + oc] + a.w * Wgt[(size_t)(k + 3) * 32 + oc];
  }
  float ls = (acc >= 0.f) ? -log1pf(expf(-acc)) : acc - log1pf(expf(acc));
  int b = tok >> 11, n = tok & 2047;
  lsg_t[((size_t)(b * 32 + oc)) * 2048 + n] = ls;
}

// ---------- scan v3: 64 blocks (b,ch), 256 thr x 8 toks, shfl wave-scan ----------
__global__ __launch_bounds__(256) void scan_kernel(const float* __restrict__ lsg_t,
                                                   const float* __restrict__ so,
                                                   float* __restrict__ khvh) {
  int b = blockIdx.x >> 5, ch = blockIdx.x & 31;
  int t = threadIdx.x, lane = t & 63, wv = t >> 6;
  const float* L = lsg_t + ((size_t)(b * 32 + ch)) * 2048 + t * 8;
  float ls[8], v[8];
  float4 a = *(const float4*)L, c = *(const float4*)(L + 4);
  ls[0] = a.x; ls[1] = a.y; ls[2] = a.z; ls[3] = a.w;
  ls[4] = c.x; ls[5] = c.y; ls[6] = c.z; ls[7] = c.w;
  const float* V = so + ((size_t)(b * 2048 + t * 8)) * 384 + 256 + ch;
#pragma unroll
  for (int j = 0; j < 8; j++) v[j] = V[(size_t)j * 384];
  // phase A: block-exclusive prefix of ls
  float run = 0.f;
#pragma unroll
  for (int j = 0; j < 8; j++) run += ls[j];
  float incl = run;
#pragma unroll
  for (int off = 1; off < 64; off <<= 1) {
    float nv = __shfl_up(incl, off);
    if (lane >= off) incl += nv;
  }
  __shared__ float ws[2][4];
  if (lane == 63) ws[0][wv] = incl;
  __syncthreads();
  float wbase = 0.f;
#pragma unroll
  for (int w = 0; w < 4; w++) wbase += (w < wv) ? ws[0][w] : 0.f;
  float baseA = wbase + incl - run;  // exclusive prefix of ls for this thread
  // phase B: local sum of v*exp(prefix)
  float lf = baseA, s = 0.f;
#pragma unroll
  for (int j = 0; j < 8; j++) { s += v[j] * __expf(lf); lf += ls[j]; }
  float incl2 = s;
#pragma unroll
  for (int off = 1; off < 64; off <<= 1) {
    float nv = __shfl_up(incl2, off);
    if (lane >= off) incl2 += nv;
  }
  if (lane == 63) ws[1][wv] = incl2;
  __syncthreads();
  float wbase2 = 0.f;
#pragma unroll
  for (int w = 0; w < 4; w++) wbase2 += (w < wv) ? ws[1][w] : 0.f;
  float base2 = wbase2 + incl2 - s;
  // phase C: emit inclusive cumsum
  lf = baseA; s = base2;
  float* O = khvh + ((size_t)(b * 2048 + t * 8)) * 32 + ch;
#pragma unroll
  for (int j = 0; j < 8; j++) { s += v[j] * __expf(lf); lf += ls[j]; O[(size_t)j * 32] = s; }
}

// ---------- rope q in place (vectorized) ----------
__global__ void rope_q(unsigned short* __restrict__ q_r, const float2* __restrict__ cs) {
  int i = blockIdx.x * 256 + threadIdx.x;  // 32*2048*8
  int fc = (i & 7) * 8;
  int n = (i >> 3) & 2047;
  int bh = i >> 14;
  unsigned short* p = q_r + ((size_t)bh * 2048 + n) * 128;
  union { unsigned short u[8]; bf16x8 v; } a, b, oa, ob;
  a.v = *(bf16x8*)(p + fc);
  b.v = *(bf16x8*)(p + 64 + fc);
#pragma unroll
  for (int j = 0; j < 8; j++) {
    float t1 = bf2f(a.u[j]), t2 = bf2f(b.u[j]);
    float2 c = cs[(n << 6) + fc + j];
    oa.u[j] = f2bf(t1 * c.x - t2 * c.y);
    ob.u[j] = f2bf(t2 * c.x + t1 * c.y);
  }
  *(bf16x8*)(p + fc) = oa.v;
  *(bf16x8*)(p + 64 + fc) = ob.v;
}

// ---------- build k_r, v_r (vectorized stores) ----------
__global__ __launch_bounds__(256) void build_kv(const float* __restrict__ small_out,
                                                const float* __restrict__ khvh,
                                                const float2* __restrict__ cs,
                                                unsigned short* __restrict__ k_r,
                                                unsigned short* __restrict__ v_r) {
  int tok = blockIdx.x;
  int b = tok >> 11, n = tok & 2047;
  __shared__ float kpr[128], vps[128], khs[16], vhs[16];
  int t = threadIdx.x;
  const float* so = small_out + (size_t)tok * 384;
  if (t < 64) {
    float k1 = so[t], k2 = so[t + 64];
    float2 c = cs[(n << 6) + t];
    kpr[t] = k1 * c.x - k2 * c.y;
    kpr[t + 64] = k2 * c.x + k1 * c.y;
  } else if (t < 192) {
    int d = t - 64;
    vps[d] = so[128 + d];
  } else if (t < 224) {
    int ch = t - 192;
    float v = khvh[(size_t)tok * 32 + ch];
    if (ch < 16) khs[ch] = v; else vhs[ch - 16] = v;
  }
  __syncthreads();
  int h = t >> 4, d0 = (t & 15) * 8;
  float kh = khs[h], vh = vhs[h];
  union { unsigned short u[8]; bf16x8 v; } ko, vo;
#pragma unroll
  for (int j = 0; j < 8; j++) {
    ko.u[j] = f2bf(kpr[d0 + j] * kh);
    vo.u[j] = f2bf(vps[d0 + j] * vh);
  }
  size_t off = (((size_t)b * 16 + h) * 2048 + n) * 128 + d0;
  *(bf16x8*)(k_r + off) = ko.v;
  *(bf16x8*)(v_r + off) = vo.v;
}

// ---------- v_t (b,h,d,n) <- v_r (b,h,n,d) ----------
__global__ __launch_bounds__(256) void transpose_v(const unsigned short* __restrict__ v_r,
                                                   unsigned short* __restrict__ v_t) {
  int nt = blockIdx.x;
  int bh = blockIdx.y;
  __shared__ unsigned short Ts[64 * 136];
  int tid = threadIdx.x;
  const unsigned short* src = v_r + ((size_t)bh * 2048 + nt * 64) * 128;
#pragma unroll
  for (int c = 0; c < 4; c++) {
    int g = c * 256 + tid;
    int r = g >> 4, ch = (g & 15) * 8;
    *(bf16x8*)&Ts[r * 136 + ch] = *(const bf16x8*)(src + r * 128 + ch);
  }
  __syncthreads();
#pragma unroll
  for (int c = 0; c < 4; c++) {
    int g = c * 256 + tid;
    int d = g >> 3, nc = (g & 7) * 8;
    union { unsigned short u[8]; bf16x8 v; } o;
#pragma unroll
    for (int j = 0; j < 8; j++) o.u[j] = Ts[(nc + j) * 136 + d];
    *(bf16x8*)(v_t + ((size_t)bh * 128 + d) * 2048 + nt * 64 + nc) = o.v;
  }
}

// ---------- m97-style NT GEMM (XCD-swizzled) ----------
template <int MODE>
__global__ __launch_bounds__(256) void gemm_bt(const unsigned short* __restrict__ A,
                                               const unsigned short* __restrict__ B,
                                               float* __restrict__ Cf,
                                               unsigned short* __restrict__ Cb,
                                               int K, int ldc) {
  __shared__ unsigned short As[128 * 32];
  __shared__ unsigned short Bs[128 * 32];
  int tid = threadIdx.x;
  int wave = tid >> 6, lane = tid & 63, l15 = lane & 15, lg = lane >> 4;
  int wr = wave >> 1, wc = wave & 1;
  // XCD-aware bijective swizzle (nwg % 8 == 0 for all launches)
  int lin = blockIdx.y * gridDim.x + blockIdx.x;
  int cpx = (gridDim.x * gridDim.y) >> 3;
  int swz = (lin & 7) * cpx + (lin >> 3);
  int bx = swz % gridDim.x, by = swz / gridDim.x;
  int row0 = by * 128, col0 = bx * 128;
  f32x4 acc[4][4];
#pragma unroll
  for (int m = 0; m < 4; m++)
#pragma unroll
    for (int n = 0; n < 4; n++) acc[m][n] = (f32x4){0.f, 0.f, 0.f, 0.f};

  for (int k0 = 0; k0 < K; k0 += 32) {
#pragma unroll
    for (int c = 0; c < 2; c++) {
      int chunk = c * 256 + tid;
      int r = chunk >> 2, kk = (chunk & 3) * 8;
      __builtin_amdgcn_global_load_lds(
          (const __attribute__((address_space(1))) void*)(A + (size_t)(row0 + r) * K + k0 + kk),
          (__attribute__((address_space(3))) void*)(As + ((size_t)c * 256 + wave * 64) * 8), 16, 0, 0);
      __builtin_amdgcn_global_load_lds(
          (const __attribute__((address_space(1))) void*)(B + (size_t)(col0 + r) * K + k0 + kk),
          (__attribute__((address_space(3))) void*)(Bs + ((size_t)c * 256 + wave * 64) * 8), 16, 0, 0);
    }
    __syncthreads();
    bf16x8 af[4], bfr[4];
#pragma unroll
    for (int m = 0; m < 4; m++) af[m] = *(const bf16x8*)&As[(wr * 64 + m * 16 + l15) * 32 + lg * 8];
#pragma unroll
    for (int n = 0; n < 4; n++) bfr[n] = *(const bf16x8*)&Bs[(wc * 64 + n * 16 + l15) * 32 + lg * 8];
#pragma unroll
    for (int m = 0; m < 4; m++)
#pragma unroll
      for (int n = 0; n < 4; n++) acc[m][n] = MFMA16(af[m], bfr[n], acc[m][n]);
    __syncthreads();
  }
#pragma unroll
  for (int m = 0; m < 4; m++) {
    int row_b = row0 + wr * 64 + m * 16 + lg * 4;
#pragma unroll
    for (int n = 0; n < 4; n++) {
      int col = col0 + wc * 64 + n * 16 + l15;
#pragma unroll
      for (int j = 0; j < 4; j++) {
        int row = row_b + j;
        if (MODE == 0) {
          Cf[(size_t)row * ldc + col] = acc[m][n][j];
        } else {
          int b = row >> 11, nn = row & 2047, h = col >> 7, d = col & 127;
          Cb[(((size_t)b * 16 + h) * 2048 + nn) * 128 + d] = f2bf(acc[m][n][j]);
        }
      }
    }
  }
}

// ---------- flash attention v3: two Q-tiles per block, dbuf staging, XCD swizzle ----------
__global__ __launch_bounds__(256, 2) void flash_attn(const unsigned short* __restrict__ q_r,
                                                     const unsigned short* __restrict__ k_r,
                                                     const unsigned short* __restrict__ v_t,
                                                     unsigned short* __restrict__ o) {
  // grid fixed 16x32 = 512; swizzle so each XCD owns 4 consecutive heads
  int lin = blockIdx.y * 16 + blockIdx.x;
  int swz = (lin & 7) * 64 + (lin >> 3);
  int bx = swz & 15, bh = swz >> 4;
  const unsigned short* Kg = k_r + (size_t)bh * 2048 * 128;
  const unsigned short* Vtg = v_t + (size_t)bh * 128 * 2048;
  __shared__ unsigned short Ks[2][64 * 128];
  __shared__ unsigned short VTs[2][128 * 64];
  __shared__ unsigned short Ps[4][16 * 72];
  int tid = threadIdx.x, wave = tid >> 6, lane = tid & 63, l15 = lane & 15, lg = lane >> 4;
  int sw = (l15 & 7) * 8;
  int b = bh >> 4, h = bh & 15;

  int qtA = bx, qtB = 31 - bx;
  int qt = qtA;
  const unsigned short* Qg = q_r + ((size_t)bh * 2048 + qt * 64) * 128;
  bf16x8 qf[4];
#pragma unroll
  for (int kk = 0; kk < 4; kk++)
    qf[kk] = *(const bf16x8*)(Qg + (wave * 16 + l15) * 128 + kk * 32 + lg * 8);

  float m_r[4], l_r[4];
  f32x4 oacc[8];
#pragma unroll
  for (int j = 0; j < 4; j++) { m_r[j] = -INFINITY; l_r[j] = 0.f; }
#pragma unroll
  for (int db = 0; db < 8; db++) oacc[db] = (f32x4){0.f, 0.f, 0.f, 0.f};

  const float scale = 0.08838834764831845f;  // 1/sqrt(128)

#define STAGE(kt, bsel)                                                                           \
  {                                                                                               \
    int kti = (kt);                                                                               \
    int bs = (bsel);                                                                              \
    _Pragma("unroll") for (int c = 0; c < 4; c++) {                                               \
      int s = c * 256 + tid;                                                                      \
      int kr = s >> 4, kc = ((s & 15) ^ (kr & 7)) * 8;                                            \
      __builtin_amdgcn_global_load_lds(                                                           \
          (const __attribute__((address_space(1))) void*)(Kg + (size_t)(kti * 64 + kr) * 128 + kc),\
          (__attribute__((address_space(3))) void*)(&Ks[bs][(c * 256 + wave * 64) * 8]), 16, 0, 0);\
      int vr = s >> 3, vc = ((s & 7) ^ (vr & 7)) * 8;                                             \
      __builtin_amdgcn_global_load_lds(                                                           \
          (const __attribute__((address_space(1))) void*)(Vtg + (size_t)vr * 2048 + kti * 64 + vc),\
          (__attribute__((address_space(3))) void*)(&VTs[bs][(c * 256 + wave * 64) * 8]), 16, 0, 0);\
    }                                                                                             \
  }

  STAGE(0, 0);
  __syncthreads();

  for (int s = 0; s < 33; ++s) {
    int nb = s & 1;
    if (s + 1 < 33) {
      int nk = (s + 1 <= qtA) ? (s + 1) : (s + 1 - (qtA + 1));
      STAGE(nk, nb ^ 1);
    }
    int kt = (s <= qtA) ? s : (s - (qtA + 1));
    bool diag = (s == qtA) || (s == 32);
    int qrow0 = qt * 64 + wave * 16 + lg * 4;

    f32x4 sc[4];
#pragma unroll
    for (int cb = 0; cb < 4; cb++) sc[cb] = (f32x4){0.f, 0.f, 0.f, 0.f};
#pragma unroll
    for (int kk = 0; kk < 4; kk++) {
#pragma unroll
      for (int cb = 0; cb < 4; cb++) {
        bf16x8 kf = *(const bf16x8*)&Ks[nb][(cb * 16 + l15) * 128 + ((kk * 32 + lg * 8) ^ sw)];
        sc[cb] = MFMA16(qf[kk], kf, sc[cb]);
      }
    }
    float pm[4] = {-INFINITY, -INFINITY, -INFINITY, -INFINITY};
    if (diag) {
#pragma unroll
      for (int cb = 0; cb < 4; cb++) {
        int col = kt * 64 + cb * 16 + l15;
#pragma unroll
        for (int j = 0; j < 4; j++) {
          float v = sc[cb][j] * scale;
          if (col > qrow0 + j) v = -INFINITY;
          sc[cb][j] = v;
          pm[j] = fmaxf(pm[j], v);
        }
      }
    } else {
#pragma unroll
      for (int cb = 0; cb < 4; cb++)
#pragma unroll
        for (int j = 0; j < 4; j++) {
          float v = sc[cb][j] * scale;
          sc[cb][j] = v;
          pm[j] = fmaxf(pm[j], v);
        }
    }
#pragma unroll
    for (int off = 1; off < 16; off <<= 1) {
#pragma unroll
      for (int j = 0; j < 4; j++) pm[j] = fmaxf(pm[j], __shfl_xor(pm[j], off));
    }
    float corr[4], rs[4];
#pragma unroll
    for (int j = 0; j < 4; j++) {
      float mn = fmaxf(m_r[j], pm[j]);
      corr[j] = __expf(m_r[j] - mn);
      m_r[j] = mn;
      rs[j] = 0.f;
    }
    float p[4][4];
#pragma unroll
    for (int cb = 0; cb < 4; cb++)
#pragma unroll
      for (int j = 0; j < 4; j++) {
        float pv = __expf(sc[cb][j] - m_r[j]);
        p[cb][j] = pv;
        rs[j] += pv;
      }
#pragma unroll
    for (int off = 1; off < 16; off <<= 1) {
#pragma unroll
      for (int j = 0; j < 4; j++) rs[j] += __shfl_xor(rs[j], off);
    }
#pragma unroll
    for (int j = 0; j < 4; j++) l_r[j] = l_r[j] * corr[j] + rs[j];
#pragma unroll
    for (int db = 0; db < 8; db++) {
      f32x4 t = oacc[db];
#pragma unroll
      for (int j = 0; j < 4; j++) t[j] *= corr[j];
      oacc[db] = t;
    }
#pragma unroll
    for (int cb = 0; cb < 4; cb++)
#pragma unroll
      for (int j = 0; j < 4; j++) Ps[wave][(lg * 4 + j) * 72 + cb * 16 + l15] = f2bf(p[cb][j]);
#pragma unroll
    for (int kc = 0; kc < 2; kc++) {
      bf16x8 pa = *(const bf16x8*)&Ps[wave][l15 * 72 + kc * 32 + lg * 8];
#pragma unroll
      for (int db = 0; db < 8; db++) {
        bf16x8 vb = *(const bf16x8*)&VTs[nb][(db * 16 + l15) * 64 + ((kc * 32 + lg * 8) ^ sw)];
        oacc[db] = MFMA16(pa, vb, oacc[db]);
      }
    }
    __syncthreads();

    if (s == qtA) {
      int qrow_e = qt * 64 + wave * 16 + lg * 4;
#pragma unroll
      for (int db = 0; db < 8; db++) {
        int d = db * 16 + l15;
#pragma unroll
        for (int j = 0; j < 4; j++) {
          float val = oacc[db][j] / l_r[j];
          o[((size_t)(b * 2048 + qrow_e + j)) * 2048 + h * 128 + d] = f2bf(val);
        }
      }
      qt = qtB;
      Qg = q_r + ((size_t)bh * 2048 + qt * 64) * 128;
#pragma unroll
      for (int kk = 0; kk < 4; kk++)
        qf[kk] = *(const bf16x8*)(Qg + (wave * 16 + l15) * 128 + kk * 32 + lg * 8);
#pragma unroll
      for (int j = 0; j < 4; j++) { m_r[j] = -INFINITY; l_r[j] = 0.f; }
#pragma unroll
      for (int db = 0; db < 8; db++) oacc[db] = (f32x4){0.f, 0.f, 0.f, 0.f};
    }
  }
  int qrow_e = qt * 64 + wave * 16 + lg * 4;
#pragma unroll
  for (int db = 0; db < 8; db++) {
    int d = db * 16 + l15;
#pragma unroll
    for (int j = 0; j < 4; j++) {
      float val = oacc[db][j] / l_r[j];
      o[((size_t)(b * 2048 + qrow_e + j)) * 2048 + h * 128 + d] = f2bf(val);
    }
  }
#undef STAGE
}

// ---------- host launch ----------
extern "C" void kernel_launch(void* const* d_in, const int* in_sizes, int n_in,
                              void* d_out, int out_size, void* d_ws, size_t ws_size,
                              hipStream_t stream) {
  (void)in_sizes; (void)n_in; (void)out_size; (void)ws_size;
  const float* x    = (const float*)d_in[0];
  const float* Wq   = (const float*)d_in[1];
  const float* Wkv  = (const float*)d_in[2];
  const float* Wkvh = (const float*)d_in[3];
  const float* Wg   = (const float*)d_in[4];
  const float* Wout = (const float*)d_in[5];
  float* out = (float*)d_out;

  char* ws = (char*)d_ws;
  size_t off = 0;
  auto alloc = [&](size_t bytes) -> void* {
    void* p = ws + off;
    off += (bytes + 255) & ~(size_t)255;
    return p;
  };
  unsigned short* x_bf    = (unsigned short*)alloc(4096ull * 2048 * 2);
  unsigned short* wq_bf   = (unsigned short*)alloc(2048ull * 2048 * 2);
  unsigned short* wout_bf = (unsigned short*)alloc(2048ull * 2048 * 2);
  unsigned short* wsm_bf  = (unsigned short*)alloc(384ull * 2048 * 2);
  unsigned short* q_r     = (unsigned short*)alloc(4096ull * 2048 * 2);
  unsigned short* k_r     = (unsigned short*)alloc(4096ull * 2048 * 2);
  unsigned short* v_r     = (unsigned short*)alloc(4096ull * 2048 * 2);
  unsigned short* o_bf    = (unsigned short*)alloc(4096ull * 2048 * 2);
  float* small_out        = (float*)alloc(4096ull * 384 * 4);
  float* lsg_t            = (float*)alloc(64ull * 2048 * 4);
  float* khvh             = (float*)alloc(4096ull * 32 * 4);
  float2* cs              = (float2*)alloc(2048ull * 64 * 8);
  float* wgt              = (float*)alloc(2048ull * 32 * 4);
  unsigned short* v_t     = x_bf;  // x_bf dead after the q/small GEMMs

  cast_f32_bf16<<<4096, 256, 0, stream>>>(x, x_bf, 4096 * 2048);
  cast_f32_bf16<<<2048, 256, 0, stream>>>(Wq, wq_bf, 2048 * 2048);
  cast_f32_bf16<<<2048, 256, 0, stream>>>(Wout, wout_bf, 2048 * 2048);
  build_wsmall<<<384, 256, 0, stream>>>(Wkv, Wkvh, wsm_bf);
  rope_table<<<512, 256, 0, stream>>>(cs);
  transpose_wg<<<256, 256, 0, stream>>>(Wg, wgt);
  gproj<<<512, 256, 0, stream>>>(x, wgt, lsg_t);
  gemm_bt<0><<<dim3(3, 32), 256, 0, stream>>>(x_bf, wsm_bf, small_out, nullptr, 2048, 384);
  gemm_bt<2><<<dim3(16, 32), 256, 0, stream>>>(x_bf, wq_bf, nullptr, q_r, 2048, 2048);
  scan_kernel<<<64, 256, 0, stream>>>(lsg_t, small_out, khvh);
  rope_q<<<2048, 256, 0, stream>>>(q_r, cs);
  build_kv<<<4096, 256, 0, stream>>>(small_out, khvh, cs, k_r, v_r);
  transpose_v<<<dim3(32, 32), 256, 0, stream>>>(v_r, v_t);
  flash_attn<<<dim3(16, 32), 256, 0, stream>>>(q_r, k_r, v_t, o_bf);
  gemm_bt<0><<<dim3(16, 32), 256, 0, stream>>>(o_bf, wout_bf, out, nullptr, 2048, 2048);
}

// Round 6
// 320.322 us; speedup vs baseline: 1.7003x; 1.1083x over previous
//
#include <hip/hip_runtime.h>
#include <hip/hip_bf16.h>
#include <math.h>

// ---------- types ----------
typedef __attribute__((ext_vector_type(8))) short bf16x8;
typedef __attribute__((ext_vector_type(4))) float f32x4;

#define MFMA16(a, b, c) __builtin_amdgcn_mfma_f32_16x16x32_bf16((a), (b), (c), 0, 0, 0)

static __device__ __forceinline__ float fast_exp2(float x) { return __builtin_amdgcn_exp2f(x); }

static __device__ __forceinline__ unsigned short f2bf(float f) {
  __hip_bfloat16 h = __float2bfloat16(f);
  unsigned short u;
  __builtin_memcpy(&u, &h, 2);
  return u;
}
static __device__ __forceinline__ float bf2f(unsigned short u) {
  unsigned int x = ((unsigned int)u) << 16;
  float f;
  __builtin_memcpy(&f, &x, 4);
  return f;
}

// ---------- merged prep: casts + wsmall + rope table + wg transpose ----------
static __device__ __forceinline__ void cast8(const float* __restrict__ src,
                                             unsigned short* __restrict__ dst, int blk, int tid) {
  int i = (blk * 256 + tid) * 8;
  float4 a = *(const float4*)(src + i);
  float4 b = *(const float4*)(src + i + 4);
  union { unsigned short u[8]; bf16x8 v; } o;
  o.u[0] = f2bf(a.x); o.u[1] = f2bf(a.y); o.u[2] = f2bf(a.z); o.u[3] = f2bf(a.w);
  o.u[4] = f2bf(b.x); o.u[5] = f2bf(b.y); o.u[6] = f2bf(b.z); o.u[7] = f2bf(b.w);
  *(bf16x8*)(dst + i) = o.v;
}

__global__ __launch_bounds__(256) void prep(const float* __restrict__ x, const float* __restrict__ Wq,
                                            const float* __restrict__ Wout, const float* __restrict__ Wkv,
                                            const float* __restrict__ Wkvh, const float* __restrict__ Wg,
                                            unsigned short* __restrict__ x_bf, unsigned short* __restrict__ wq_bf,
                                            unsigned short* __restrict__ wout_bf, unsigned short* __restrict__ wsm_bf,
                                            float2* __restrict__ cs, float* __restrict__ wgt) {
  int bid = blockIdx.x, tid = threadIdx.x;
  if (bid < 4096) {
    cast8(x, x_bf, bid, tid);
  } else if (bid < 6144) {
    cast8(Wq, wq_bf, bid - 4096, tid);
  } else if (bid < 8192) {
    cast8(Wout, wout_bf, bid - 6144, tid);
  } else if (bid < 8576) {
    int row = bid - 8192;
    int c = tid * 8;
    const float* src = nullptr;
    if (row < 256) src = Wkv + (size_t)row * 2048;
    else if (row < 288) src = Wkvh + (size_t)(row - 256) * 2048;
    union { unsigned short u[8]; bf16x8 v; } o;
    if (src) {
      float4 a = *(const float4*)(src + c);
      float4 b = *(const float4*)(src + c + 4);
      o.u[0] = f2bf(a.x); o.u[1] = f2bf(a.y); o.u[2] = f2bf(a.z); o.u[3] = f2bf(a.w);
      o.u[4] = f2bf(b.x); o.u[5] = f2bf(b.y); o.u[6] = f2bf(b.z); o.u[7] = f2bf(b.w);
    } else {
      for (int j = 0; j < 8; j++) o.u[j] = 0;
    }
    *(bf16x8*)(wsm_bf + (size_t)row * 2048 + c) = o.v;
  } else if (bid < 9088) {
    int i = (bid - 8576) * 256 + tid;
    int f = i & 63, n = i >> 6;
    float inv = powf(10000.0f, -(float)(2 * f) / 128.0f);
    float ang = (float)n * inv;
    cs[i] = make_float2(cosf(ang), sinf(ang));
  } else {
    int i = (bid - 9088) * 256 + tid;
    int oc = i >> 11, k = i & 2047;
    wgt[(size_t)k * 32 + oc] = Wg[i];
  }
}

// ---------- lsg_t[b][ch][n] = log_sigmoid(x @ Wg^T), transposed write ----------
__global__ __launch_bounds__(256) void gproj(const float* __restrict__ x, const float* __restrict__ Wgt,
                                             float* __restrict__ lsg_t) {
  int tid = blockIdx.x * 256 + threadIdx.x;  // 4096*32
  int tok = tid >> 5, oc = tid & 31;
  const float* xr = x + (size_t)tok * 2048;
  float acc = 0.f;
  for (int k = 0; k < 2048; k += 4) {
    float4 a = *(const float4*)(xr + k);
    acc += a.x * Wgt[(size_t)k * 32 + oc] + a.y * Wgt[(size_t)(k + 1) * 32 + oc] +
           a.z * Wgt[(size_t)(k + 2) * 32 + oc] + a.w * Wgt[(size_t)(k + 3) * 32 + oc];
  }
  float ls = (acc >= 0.f) ? -log1pf(expf(-acc)) : acc - log1pf(expf(acc));
  int b = tok >> 11, n = tok & 2047;
  lsg_t[((size_t)(b * 32 + oc)) * 2048 + n] = ls;
}

// ---------- scan v3: 64 blocks (b,ch), 256 thr x 8 toks, shfl wave-scan ----------
__global__ __launch_bounds__(256) void scan_kernel(const float* __restrict__ lsg_t,
                                                   const float* __restrict__ so,
                                                   float* __restrict__ khvh) {
  int b = blockIdx.x >> 5, ch = blockIdx.x & 31;
  int t = threadIdx.x, lane = t & 63, wv = t >> 6;
  const float* L = lsg_t + ((size_t)(b * 32 + ch)) * 2048 + t * 8;
  float ls[8], v[8];
  float4 a = *(const float4*)L, c = *(const float4*)(L + 4);
  ls[0] = a.x; ls[1] = a.y; ls[2] = a.z; ls[3] = a.w;
  ls[4] = c.x; ls[5] = c.y; ls[6] = c.z; ls[7] = c.w;
  const float* V = so + ((size_t)(b * 2048 + t * 8)) * 384 + 256 + ch;
#pragma unroll
  for (int j = 0; j < 8; j++) v[j] = V[(size_t)j * 384];
  float run = 0.f;
#pragma unroll
  for (int j = 0; j < 8; j++) run += ls[j];
  float incl = run;
#pragma unroll
  for (int off = 1; off < 64; off <<= 1) {
    float nv = __shfl_up(incl, off);
    if (lane >= off) incl += nv;
  }
  __shared__ float ws[2][4];
  if (lane == 63) ws[0][wv] = incl;
  __syncthreads();
  float wbase = 0.f;
#pragma unroll
  for (int w = 0; w < 4; w++) wbase += (w < wv) ? ws[0][w] : 0.f;
  float baseA = wbase + incl - run;
  float lf = baseA, s = 0.f;
#pragma unroll
  for (int j = 0; j < 8; j++) { s += v[j] * __expf(lf); lf += ls[j]; }
  float incl2 = s;
#pragma unroll
  for (int off = 1; off < 64; off <<= 1) {
    float nv = __shfl_up(incl2, off);
    if (lane >= off) incl2 += nv;
  }
  if (lane == 63) ws[1][wv] = incl2;
  __syncthreads();
  float wbase2 = 0.f;
#pragma unroll
  for (int w = 0; w < 4; w++) wbase2 += (w < wv) ? ws[1][w] : 0.f;
  float base2 = wbase2 + incl2 - s;
  lf = baseA; s = base2;
  float* O = khvh + ((size_t)(b * 2048 + t * 8)) * 32 + ch;
#pragma unroll
  for (int j = 0; j < 8; j++) { s += v[j] * __expf(lf); lf += ls[j]; O[(size_t)j * 32] = s; }
}

// ---------- build k_r, v_r (vectorized stores) ----------
__global__ __launch_bounds__(256) void build_kv(const float* __restrict__ small_out,
                                                const float* __restrict__ khvh,
                                                const float2* __restrict__ cs,
                                                unsigned short* __restrict__ k_r,
                                                unsigned short* __restrict__ v_r) {
  int tok = blockIdx.x;
  int b = tok >> 11, n = tok & 2047;
  __shared__ float kpr[128], vps[128], khs[16], vhs[16];
  int t = threadIdx.x;
  const float* so = small_out + (size_t)tok * 384;
  if (t < 64) {
    float k1 = so[t], k2 = so[t + 64];
    float2 c = cs[(n << 6) + t];
    kpr[t] = k1 * c.x - k2 * c.y;
    kpr[t + 64] = k2 * c.x + k1 * c.y;
  } else if (t < 192) {
    int d = t - 64;
    vps[d] = so[128 + d];
  } else if (t < 224) {
    int ch = t - 192;
    float v = khvh[(size_t)tok * 32 + ch];
    if (ch < 16) khs[ch] = v; else vhs[ch - 16] = v;
  }
  __syncthreads();
  int h = t >> 4, d0 = (t & 15) * 8;
  float kh = khs[h], vh = vhs[h];
  union { unsigned short u[8]; bf16x8 v; } ko, vo;
#pragma unroll
  for (int j = 0; j < 8; j++) {
    ko.u[j] = f2bf(kpr[d0 + j] * kh);
    vo.u[j] = f2bf(vps[d0 + j] * vh);
  }
  size_t off = (((size_t)b * 16 + h) * 2048 + n) * 128 + d0;
  *(bf16x8*)(k_r + off) = ko.v;
  *(bf16x8*)(v_r + off) = vo.v;
}

// ---------- v_t (b,h,d,n) <- v_r (b,h,n,d) ----------
__global__ __launch_bounds__(256) void transpose_v(const unsigned short* __restrict__ v_r,
                                                   unsigned short* __restrict__ v_t) {
  int nt = blockIdx.x;
  int bh = blockIdx.y;
  __shared__ unsigned short Ts[64 * 136];
  int tid = threadIdx.x;
  const unsigned short* src = v_r + ((size_t)bh * 2048 + nt * 64) * 128;
#pragma unroll
  for (int c = 0; c < 4; c++) {
    int g = c * 256 + tid;
    int r = g >> 4, ch = (g & 15) * 8;
    *(bf16x8*)&Ts[r * 136 + ch] = *(const bf16x8*)(src + r * 128 + ch);
  }
  __syncthreads();
#pragma unroll
  for (int c = 0; c < 4; c++) {
    int g = c * 256 + tid;
    int d = g >> 3, nc = (g & 7) * 8;
    union { unsigned short u[8]; bf16x8 v; } o;
#pragma unroll
    for (int j = 0; j < 8; j++) o.u[j] = Ts[(nc + j) * 136 + d];
    *(bf16x8*)(v_t + ((size_t)bh * 128 + d) * 2048 + nt * 64 + nc) = o.v;
  }
}

// ---------- m97-style NT GEMM (XCD-swizzled) ----------
template <int MODE>
__global__ __launch_bounds__(256) void gemm_bt(const unsigned short* __restrict__ A,
                                               const unsigned short* __restrict__ B,
                                               float* __restrict__ Cf,
                                               unsigned short* __restrict__ Cb,
                                               int K, int ldc) {
  __shared__ unsigned short As[128 * 32];
  __shared__ unsigned short Bs[128 * 32];
  int tid = threadIdx.x;
  int wave = tid >> 6, lane = tid & 63, l15 = lane & 15, lg = lane >> 4;
  int wr = wave >> 1, wc = wave & 1;
  int lin = blockIdx.y * gridDim.x + blockIdx.x;
  int cpx = (gridDim.x * gridDim.y) >> 3;
  int swz = (lin & 7) * cpx + (lin >> 3);
  int bx = swz % gridDim.x, by = swz / gridDim.x;
  int row0 = by * 128, col0 = bx * 128;
  f32x4 acc[4][4];
#pragma unroll
  for (int m = 0; m < 4; m++)
#pragma unroll
    for (int n = 0; n < 4; n++) acc[m][n] = (f32x4){0.f, 0.f, 0.f, 0.f};

  for (int k0 = 0; k0 < K; k0 += 32) {
#pragma unroll
    for (int c = 0; c < 2; c++) {
      int chunk = c * 256 + tid;
      int r = chunk >> 2, kk = (chunk & 3) * 8;
      __builtin_amdgcn_global_load_lds(
          (const __attribute__((address_space(1))) void*)(A + (size_t)(row0 + r) * K + k0 + kk),
          (__attribute__((address_space(3))) void*)(As + ((size_t)c * 256 + wave * 64) * 8), 16, 0, 0);
      __builtin_amdgcn_global_load_lds(
          (const __attribute__((address_space(1))) void*)(B + (size_t)(col0 + r) * K + k0 + kk),
          (__attribute__((address_space(3))) void*)(Bs + ((size_t)c * 256 + wave * 64) * 8), 16, 0, 0);
    }
    __syncthreads();
    bf16x8 af[4], bfr[4];
#pragma unroll
    for (int m = 0; m < 4; m++) af[m] = *(const bf16x8*)&As[(wr * 64 + m * 16 + l15) * 32 + lg * 8];
#pragma unroll
    for (int n = 0; n < 4; n++) bfr[n] = *(const bf16x8*)&Bs[(wc * 64 + n * 16 + l15) * 32 + lg * 8];
#pragma unroll
    for (int m = 0; m < 4; m++)
#pragma unroll
      for (int n = 0; n < 4; n++) acc[m][n] = MFMA16(af[m], bfr[n], acc[m][n]);
    __syncthreads();
  }
#pragma unroll
  for (int m = 0; m < 4; m++) {
    int row_b = row0 + wr * 64 + m * 16 + lg * 4;
#pragma unroll
    for (int n = 0; n < 4; n++) {
      int col = col0 + wc * 64 + n * 16 + l15;
#pragma unroll
      for (int j = 0; j < 4; j++) {
        int row = row_b + j;
        if (MODE == 0) {
          Cf[(size_t)row * ldc + col] = acc[m][n][j];
        } else {
          int b = row >> 11, nn = row & 2047, h = col >> 7, d = col & 127;
          Cb[(((size_t)b * 16 + h) * 2048 + nn) * 128 + d] = f2bf(acc[m][n][j]);
        }
      }
    }
  }
}

// ---------- flash attention v4: fused Q-rope, exp2 domain, MFMA row-sum, defer-max ----------
__global__ __launch_bounds__(256, 2) void flash_attn(const unsigned short* __restrict__ q_r,
                                                     const unsigned short* __restrict__ k_r,
                                                     const unsigned short* __restrict__ v_t,
                                                     const float2* __restrict__ cs,
                                                     unsigned short* __restrict__ o) {
  int lin = blockIdx.y * 16 + blockIdx.x;
  int swz = (lin & 7) * 64 + (lin >> 3);
  int bx = swz & 15, bh = swz >> 4;
  const unsigned short* Kg = k_r + (size_t)bh * 2048 * 128;
  const unsigned short* Vtg = v_t + (size_t)bh * 128 * 2048;
  __shared__ unsigned short Ks[2][64 * 128];
  __shared__ unsigned short VTs[2][128 * 64];
  __shared__ unsigned short Ps[4][16 * 72];
  int tid = threadIdx.x, wave = tid >> 6, lane = tid & 63, l15 = lane & 15, lg = lane >> 4;
  int sw = (l15 & 7) * 8;
  int b = bh >> 4, h = bh & 15;

  // all-ones bf16 fragment for MFMA row-sum
  union { unsigned short u[8]; bf16x8 v; } onesu;
#pragma unroll
  for (int j = 0; j < 8; j++) onesu.u[j] = 0x3F80;
  const bf16x8 ones = onesu.v;

  int qtA = bx, qtB = 31 - bx;
  int qt = qtA;

  bf16x8 qf[4];
  // fused RoPE Q-fragment load
#define LOAD_Q()                                                                                   \
  {                                                                                                \
    const unsigned short* Qg = q_r + ((size_t)bh * 2048 + qt * 64) * 128;                          \
    int n = qt * 64 + wave * 16 + l15;                                                             \
    union { unsigned short u[8]; bf16x8 v; } r0, r1, r2, r3;                                       \
    r0.v = *(const bf16x8*)(Qg + (wave * 16 + l15) * 128 + 0 * 32 + lg * 8);                       \
    r1.v = *(const bf16x8*)(Qg + (wave * 16 + l15) * 128 + 1 * 32 + lg * 8);                       \
    r2.v = *(const bf16x8*)(Qg + (wave * 16 + l15) * 128 + 2 * 32 + lg * 8);                       \
    r3.v = *(const bf16x8*)(Qg + (wave * 16 + l15) * 128 + 3 * 32 + lg * 8);                       \
    union { unsigned short u[8]; bf16x8 v; } o0, o1, o2, o3;                                       \
    _Pragma("unroll") for (int j = 0; j < 8; j++) {                                                \
      float2 c0 = cs[(n << 6) + 0 * 32 + lg * 8 + j];                                              \
      float t1 = bf2f(r0.u[j]), t2 = bf2f(r2.u[j]);                                                \
      o0.u[j] = f2bf(t1 * c0.x - t2 * c0.y);                                                       \
      o2.u[j] = f2bf(t2 * c0.x + t1 * c0.y);                                                       \
      float2 c1 = cs[(n << 6) + 1 * 32 + lg * 8 + j];                                              \
      float s1 = bf2f(r1.u[j]), s2 = bf2f(r3.u[j]);                                                \
      o1.u[j] = f2bf(s1 * c1.x - s2 * c1.y);                                                       \
      o3.u[j] = f2bf(s2 * c1.x + s1 * c1.y);                                                       \
    }                                                                                              \
    qf[0] = o0.v; qf[1] = o1.v; qf[2] = o2.v; qf[3] = o3.v;                                        \
  }

  LOAD_Q();

  float m_r[4], l_r[4];
  f32x4 oacc[8];
#pragma unroll
  for (int j = 0; j < 4; j++) { m_r[j] = -INFINITY; l_r[j] = 0.f; }
#pragma unroll
  for (int db = 0; db < 8; db++) oacc[db] = (f32x4){0.f, 0.f, 0.f, 0.f};

  const float kscale = 0.12753102f;  // (1/sqrt(128)) * log2(e)
  const float THR = 11.0f;           // defer-max threshold (log2 domain, < 8 nats)

#define STAGE(kt, bsel)                                                                           \
  {                                                                                               \
    int kti = (kt);                                                                               \
    int bs = (bsel);                                                                              \
    _Pragma("unroll") for (int c = 0; c < 4; c++) {                                               \
      int s = c * 256 + tid;                                                                      \
      int kr = s >> 4, kc = ((s & 15) ^ (kr & 7)) * 8;                                            \
      __builtin_amdgcn_global_load_lds(                                                           \
          (const __attribute__((address_space(1))) void*)(Kg + (size_t)(kti * 64 + kr) * 128 + kc),\
          (__attribute__((address_space(3))) void*)(&Ks[bs][(c * 256 + wave * 64) * 8]), 16, 0, 0);\
      int vr = s >> 3, vc = ((s & 7) ^ (vr & 7)) * 8;                                             \
      __builtin_amdgcn_global_load_lds(                                                           \
          (const __attribute__((address_space(1))) void*)(Vtg + (size_t)vr * 2048 + kti * 64 + vc),\
          (__attribute__((address_space(3))) void*)(&VTs[bs][(c * 256 + wave * 64) * 8]), 16, 0, 0);\
    }                                                                                             \
  }

  STAGE(0, 0);
  __syncthreads();

  for (int s = 0; s < 33; ++s) {
    int nb = s & 1;
    if (s + 1 < 33) {
      int nk = (s + 1 <= qtA) ? (s + 1) : (s + 1 - (qtA + 1));
      STAGE(nk, nb ^ 1);
    }
    int kt = (s <= qtA) ? s : (s - (qtA + 1));
    bool diag = (s == qtA) || (s == 32);
    int qrow0 = qt * 64 + wave * 16 + lg * 4;

    f32x4 sc[4];
#pragma unroll
    for (int cb = 0; cb < 4; cb++) sc[cb] = (f32x4){0.f, 0.f, 0.f, 0.f};
    __builtin_amdgcn_s_setprio(1);
#pragma unroll
    for (int kk = 0; kk < 4; kk++) {
#pragma unroll
      for (int cb = 0; cb < 4; cb++) {
        bf16x8 kf = *(const bf16x8*)&Ks[nb][(cb * 16 + l15) * 128 + ((kk * 32 + lg * 8) ^ sw)];
        sc[cb] = MFMA16(qf[kk], kf, sc[cb]);
      }
    }
    __builtin_amdgcn_s_setprio(0);
    // scale into log2 domain + causal mask + per-lane row max
    if (diag) {
#pragma unroll
      for (int cb = 0; cb < 4; cb++) {
        int col = kt * 64 + cb * 16 + l15;
#pragma unroll
        for (int j = 0; j < 4; j++) {
          float v = sc[cb][j] * kscale;
          if (col > qrow0 + j) v = -INFINITY;
          sc[cb][j] = v;
        }
      }
    } else {
#pragma unroll
      for (int cb = 0; cb < 4; cb++)
#pragma unroll
        for (int j = 0; j < 4; j++) sc[cb][j] *= kscale;
    }
    float pm[4];
#pragma unroll
    for (int j = 0; j < 4; j++)
      pm[j] = fmaxf(fmaxf(sc[0][j], sc[1][j]), fmaxf(sc[2][j], sc[3][j]));
    // defer-max: skip cross-lane reduce + rescale when no row grew past THR
    bool grow = !__all((pm[0] <= m_r[0] + THR) & (pm[1] <= m_r[1] + THR) &
                       (pm[2] <= m_r[2] + THR) & (pm[3] <= m_r[3] + THR));
    if (grow) {
#pragma unroll
      for (int off = 1; off < 16; off <<= 1) {
#pragma unroll
        for (int j = 0; j < 4; j++) pm[j] = fmaxf(pm[j], __shfl_xor(pm[j], off));
      }
#pragma unroll
      for (int j = 0; j < 4; j++) {
        float mn = fmaxf(m_r[j], pm[j]);
        float corr = fast_exp2(m_r[j] - mn);
        m_r[j] = mn;
        l_r[j] *= corr;
#pragma unroll
        for (int db = 0; db < 8; db++) oacc[db][j] *= corr;
      }
    }
    // P = exp2(s - m), pack to LDS
#pragma unroll
    for (int cb = 0; cb < 4; cb++)
#pragma unroll
      for (int j = 0; j < 4; j++)
        Ps[wave][(lg * 4 + j) * 72 + cb * 16 + l15] = f2bf(fast_exp2(sc[cb][j] - m_r[j]));
    // PV + MFMA row-sum
    f32x4 sacc = (f32x4){0.f, 0.f, 0.f, 0.f};
    __builtin_amdgcn_s_setprio(1);
#pragma unroll
    for (int kc = 0; kc < 2; kc++) {
      bf16x8 pa = *(const bf16x8*)&Ps[wave][l15 * 72 + kc * 32 + lg * 8];
      sacc = MFMA16(pa, ones, sacc);
#pragma unroll
      for (int db = 0; db < 8; db++) {
        bf16x8 vb = *(const bf16x8*)&VTs[nb][(db * 16 + l15) * 64 + ((kc * 32 + lg * 8) ^ sw)];
        oacc[db] = MFMA16(pa, vb, oacc[db]);
      }
    }
    __builtin_amdgcn_s_setprio(0);
#pragma unroll
    for (int j = 0; j < 4; j++) l_r[j] += sacc[j];
    __syncthreads();

    if (s == qtA) {
      int qrow_e = qt * 64 + wave * 16 + lg * 4;
#pragma unroll
      for (int db = 0; db < 8; db++) {
        int d = db * 16 + l15;
#pragma unroll
        for (int j = 0; j < 4; j++) {
          float val = oacc[db][j] / l_r[j];
          o[((size_t)(b * 2048 + qrow_e + j)) * 2048 + h * 128 + d] = f2bf(val);
        }
      }
      qt = qtB;
      LOAD_Q();
#pragma unroll
      for (int j = 0; j < 4; j++) { m_r[j] = -INFINITY; l_r[j] = 0.f; }
#pragma unroll
      for (int db = 0; db < 8; db++) oacc[db] = (f32x4){0.f, 0.f, 0.f, 0.f};
    }
  }
  int qrow_e = qt * 64 + wave * 16 + lg * 4;
#pragma unroll
  for (int db = 0; db < 8; db++) {
    int d = db * 16 + l15;
#pragma unroll
    for (int j = 0; j < 4; j++) {
      float val = oacc[db][j] / l_r[j];
      o[((size_t)(b * 2048 + qrow_e + j)) * 2048 + h * 128 + d] = f2bf(val);
    }
  }
#undef STAGE
#undef LOAD_Q
}

// ---------- host launch ----------
extern "C" void kernel_launch(void* const* d_in, const int* in_sizes, int n_in,
                              void* d_out, int out_size, void* d_ws, size_t ws_size,
                              hipStream_t stream) {
  (void)in_sizes; (void)n_in; (void)out_size; (void)ws_size;
  const float* x    = (const float*)d_in[0];
  const float* Wq   = (const float*)d_in[1];
  const float* Wkv  = (const float*)d_in[2];
  const float* Wkvh = (const float*)d_in[3];
  const float* Wg   = (const float*)d_in[4];
  const float* Wout = (const float*)d_in[5];
  float* out = (float*)d_out;

  char* ws = (char*)d_ws;
  size_t off = 0;
  auto alloc = [&](size_t bytes) -> void* {
    void* p = ws + off;
    off += (bytes + 255) & ~(size_t)255;
    return p;
  };
  unsigned short* x_bf    = (unsigned short*)alloc(4096ull * 2048 * 2);
  unsigned short* wq_bf   = (unsigned short*)alloc(2048ull * 2048 * 2);
  unsigned short* wout_bf = (unsigned short*)alloc(2048ull * 2048 * 2);
  unsigned short* wsm_bf  = (unsigned short*)alloc(384ull * 2048 * 2);
  unsigned short* q_r     = (unsigned short*)alloc(4096ull * 2048 * 2);
  unsigned short* k_r     = (unsigned short*)alloc(4096ull * 2048 * 2);
  unsigned short* v_r     = (unsigned short*)alloc(4096ull * 2048 * 2);
  unsigned short* o_bf    = (unsigned short*)alloc(4096ull * 2048 * 2);
  float* small_out        = (float*)alloc(4096ull * 384 * 4);
  float* lsg_t            = (float*)alloc(64ull * 2048 * 4);
  float* khvh             = (float*)alloc(4096ull * 32 * 4);
  float2* cs              = (float2*)alloc(2048ull * 64 * 8);
  float* wgt              = (float*)alloc(2048ull * 32 * 4);
  unsigned short* v_t     = x_bf;  // x_bf dead after the q/small GEMMs

  prep<<<9344, 256, 0, stream>>>(x, Wq, Wout, Wkv, Wkvh, Wg, x_bf, wq_bf, wout_bf, wsm_bf, cs, wgt);
  gproj<<<512, 256, 0, stream>>>(x, wgt, lsg_t);
  gemm_bt<0><<<dim3(3, 32), 256, 0, stream>>>(x_bf, wsm_bf, small_out, nullptr, 2048, 384);
  gemm_bt<2><<<dim3(16, 32), 256, 0, stream>>>(x_bf, wq_bf, nullptr, q_r, 2048, 2048);
  scan_kernel<<<64, 256, 0, stream>>>(lsg_t, small_out, khvh);
  build_kv<<<4096, 256, 0, stream>>>(small_out, khvh, cs, k_r, v_r);
  transpose_v<<<dim3(32, 32), 256, 0, stream>>>(v_r, v_t);
  flash_attn<<<dim3(16, 32), 256, 0, stream>>>(q_r, k_r, v_t, cs, o_bf);
  gemm_bt<0><<<dim3(16, 32), 256, 0, stream>>>(o_bf, wout_bf, out, nullptr, 2048, 2048);
}

// Round 7
// 303.377 us; speedup vs baseline: 1.7952x; 1.0559x over previous
//
#include <hip/hip_runtime.h>
#include <hip/hip_bf16.h>
#include <math.h>

// ---------- types ----------
typedef __attribute__((ext_vector_type(8))) short bf16x8;
typedef __attribute__((ext_vector_type(4))) float f32x4;

#define MFMA16(a, b, c) __builtin_amdgcn_mfma_f32_16x16x32_bf16((a), (b), (c), 0, 0, 0)

static __device__ __forceinline__ float fast_exp2(float x) { return __builtin_amdgcn_exp2f(x); }

static __device__ __forceinline__ unsigned short f2bf(float f) {
  __hip_bfloat16 h = __float2bfloat16(f);
  unsigned short u;
  __builtin_memcpy(&u, &h, 2);
  return u;
}
static __device__ __forceinline__ float bf2f(unsigned short u) {
  unsigned int x = ((unsigned int)u) << 16;
  float f;
  __builtin_memcpy(&f, &x, 4);
  return f;
}

// ---------- merged prep: casts + wsmall + rope table + wg transpose ----------
static __device__ __forceinline__ void cast8(const float* __restrict__ src,
                                             unsigned short* __restrict__ dst, int blk, int tid) {
  int i = (blk * 256 + tid) * 8;
  float4 a = *(const float4*)(src + i);
  float4 b = *(const float4*)(src + i + 4);
  union { unsigned short u[8]; bf16x8 v; } o;
  o.u[0] = f2bf(a.x); o.u[1] = f2bf(a.y); o.u[2] = f2bf(a.z); o.u[3] = f2bf(a.w);
  o.u[4] = f2bf(b.x); o.u[5] = f2bf(b.y); o.u[6] = f2bf(b.z); o.u[7] = f2bf(b.w);
  *(bf16x8*)(dst + i) = o.v;
}

__global__ __launch_bounds__(256) void prep(const float* __restrict__ x, const float* __restrict__ Wq,
                                            const float* __restrict__ Wout, const float* __restrict__ Wkv,
                                            const float* __restrict__ Wkvh, const float* __restrict__ Wg,
                                            unsigned short* __restrict__ x_bf, unsigned short* __restrict__ wq_bf,
                                            unsigned short* __restrict__ wout_bf, unsigned short* __restrict__ wsm_bf,
                                            float2* __restrict__ cs, float* __restrict__ wgt) {
  int bid = blockIdx.x, tid = threadIdx.x;
  if (bid < 4096) {
    cast8(x, x_bf, bid, tid);
  } else if (bid < 6144) {
    cast8(Wq, wq_bf, bid - 4096, tid);
  } else if (bid < 8192) {
    cast8(Wout, wout_bf, bid - 6144, tid);
  } else if (bid < 8576) {
    int row = bid - 8192;
    int c = tid * 8;
    const float* src = nullptr;
    if (row < 256) src = Wkv + (size_t)row * 2048;
    else if (row < 288) src = Wkvh + (size_t)(row - 256) * 2048;
    union { unsigned short u[8]; bf16x8 v; } o;
    if (src) {
      float4 a = *(const float4*)(src + c);
      float4 b = *(const float4*)(src + c + 4);
      o.u[0] = f2bf(a.x); o.u[1] = f2bf(a.y); o.u[2] = f2bf(a.z); o.u[3] = f2bf(a.w);
      o.u[4] = f2bf(b.x); o.u[5] = f2bf(b.y); o.u[6] = f2bf(b.z); o.u[7] = f2bf(b.w);
    } else {
      for (int j = 0; j < 8; j++) o.u[j] = 0;
    }
    *(bf16x8*)(wsm_bf + (size_t)row * 2048 + c) = o.v;
  } else if (bid < 9088) {
    int i = (bid - 8576) * 256 + tid;
    int f = i & 63, n = i >> 6;
    float inv = powf(10000.0f, -(float)(2 * f) / 128.0f);
    float ang = (float)n * inv;
    cs[i] = make_float2(cosf(ang), sinf(ang));
  } else {
    int i = (bid - 9088) * 256 + tid;
    int oc = i >> 11, k = i & 2047;
    wgt[(size_t)k * 32 + oc] = Wg[i];
  }
}

// ---------- lsg_t[b][ch][n] = log_sigmoid(x @ Wg^T), transposed write ----------
__global__ __launch_bounds__(256) void gproj(const float* __restrict__ x, const float* __restrict__ Wgt,
                                             float* __restrict__ lsg_t) {
  int tid = blockIdx.x * 256 + threadIdx.x;  // 4096*32
  int tok = tid >> 5, oc = tid & 31;
  const float* xr = x + (size_t)tok * 2048;
  float acc = 0.f;
  for (int k = 0; k < 2048; k += 4) {
    float4 a = *(const float4*)(xr + k);
    acc += a.x * Wgt[(size_t)k * 32 + oc] + a.y * Wgt[(size_t)(k + 1) * 32 + oc] +
           a.z * Wgt[(size_t)(k + 2) * 32 + oc] + a.w * Wgt[(size_t)(k + 3) * 32 + oc];
  }
  float ls = (acc >= 0.f) ? -log1pf(expf(-acc)) : acc - log1pf(expf(acc));
  int b = tok >> 11, n = tok & 2047;
  lsg_t[((size_t)(b * 32 + oc)) * 2048 + n] = ls;
}

// ---------- scan v3: 64 blocks (b,ch), 256 thr x 8 toks, shfl wave-scan ----------
__global__ __launch_bounds__(256) void scan_kernel(const float* __restrict__ lsg_t,
                                                   const float* __restrict__ so,
                                                   float* __restrict__ khvh) {
  int b = blockIdx.x >> 5, ch = blockIdx.x & 31;
  int t = threadIdx.x, lane = t & 63, wv = t >> 6;
  const float* L = lsg_t + ((size_t)(b * 32 + ch)) * 2048 + t * 8;
  float ls[8], v[8];
  float4 a = *(const float4*)L, c = *(const float4*)(L + 4);
  ls[0] = a.x; ls[1] = a.y; ls[2] = a.z; ls[3] = a.w;
  ls[4] = c.x; ls[5] = c.y; ls[6] = c.z; ls[7] = c.w;
  const float* V = so + ((size_t)(b * 2048 + t * 8)) * 384 + 256 + ch;
#pragma unroll
  for (int j = 0; j < 8; j++) v[j] = V[(size_t)j * 384];
  float run = 0.f;
#pragma unroll
  for (int j = 0; j < 8; j++) run += ls[j];
  float incl = run;
#pragma unroll
  for (int off = 1; off < 64; off <<= 1) {
    float nv = __shfl_up(incl, off);
    if (lane >= off) incl += nv;
  }
  __shared__ float ws[2][4];
  if (lane == 63) ws[0][wv] = incl;
  __syncthreads();
  float wbase = 0.f;
#pragma unroll
  for (int w = 0; w < 4; w++) wbase += (w < wv) ? ws[0][w] : 0.f;
  float baseA = wbase + incl - run;
  float lf = baseA, s = 0.f;
#pragma unroll
  for (int j = 0; j < 8; j++) { s += v[j] * __expf(lf); lf += ls[j]; }
  float incl2 = s;
#pragma unroll
  for (int off = 1; off < 64; off <<= 1) {
    float nv = __shfl_up(incl2, off);
    if (lane >= off) incl2 += nv;
  }
  if (lane == 63) ws[1][wv] = incl2;
  __syncthreads();
  float wbase2 = 0.f;
#pragma unroll
  for (int w = 0; w < 4; w++) wbase2 += (w < wv) ? ws[1][w] : 0.f;
  float base2 = wbase2 + incl2 - s;
  lf = baseA; s = base2;
  float* O = khvh + ((size_t)(b * 2048 + t * 8)) * 32 + ch;
#pragma unroll
  for (int j = 0; j < 8; j++) { s += v[j] * __expf(lf); lf += ls[j]; O[(size_t)j * 32] = s; }
}

// ---------- build_kv2: merged k_r build (+rope) and v_t transposed build ----------
// grid (32 n-tiles, 32 bh); k_r (b,h,n,d); v_t (b,h,d,n)
__global__ __launch_bounds__(256) void build_kv2(const float* __restrict__ so,
                                                 const float* __restrict__ khvh,
                                                 const float2* __restrict__ cs,
                                                 unsigned short* __restrict__ k_r,
                                                 unsigned short* __restrict__ v_t) {
  int ntb = blockIdx.x, bh = blockIdx.y;
  int b = bh >> 4, h = bh & 15;
  int tok0 = b * 2048 + ntb * 64;
  int n0 = ntb * 64;
  __shared__ float khs[64], vhs[64];
  __shared__ unsigned short Vt_s[64 * 132];
  int t = threadIdx.x;
  if (t < 64) {
    khs[t] = khvh[(size_t)(tok0 + t) * 32 + h];
    vhs[t] = khvh[(size_t)(tok0 + t) * 32 + 16 + h];
  }
  __syncthreads();
  // K phase: 64 tok x 16 first-half quads, rope pair (d, d+64)
#pragma unroll
  for (int c = 0; c < 4; c++) {
    int idx = c * 256 + t;
    int r = idx >> 4, q4 = (idx & 15) * 4;
    const float* sop = so + (size_t)(tok0 + r) * 384;
    float4 k1 = *(const float4*)(sop + q4);
    float4 k2 = *(const float4*)(sop + 64 + q4);
    float kh = khs[r];
    int n = n0 + r;
    union { unsigned short u[4]; uint2 v2; } o1, o2;
#pragma unroll
    for (int j = 0; j < 4; j++) {
      float2 cc = cs[(n << 6) + q4 + j];
      float av = ((const float*)&k1)[j], bv = ((const float*)&k2)[j];
      o1.u[j] = f2bf((av * cc.x - bv * cc.y) * kh);
      o2.u[j] = f2bf((bv * cc.x + av * cc.y) * kh);
    }
    size_t off = ((size_t)bh * 2048 + n) * 128 + q4;
    *(uint2*)(k_r + off) = o1.v2;
    *(uint2*)(k_r + off + 64) = o2.v2;
  }
  // V phase: 64 tok x 32 quads -> LDS bf16
#pragma unroll
  for (int c = 0; c < 8; c++) {
    int idx = c * 256 + t;
    int r = idx >> 5, d4 = (idx & 31) * 4;
    const float* sop = so + (size_t)(tok0 + r) * 384 + 128;
    float4 v = *(const float4*)(sop + d4);
    float vh = vhs[r];
    union { unsigned short u[4]; uint2 v2; } ov;
#pragma unroll
    for (int j = 0; j < 4; j++) ov.u[j] = f2bf(((const float*)&v)[j] * vh);
    *(uint2*)&Vt_s[r * 132 + d4] = ov.v2;
  }
  __syncthreads();
  // transpose out: 128 d x 8 col-groups
#pragma unroll
  for (int c = 0; c < 4; c++) {
    int idx = c * 256 + t;
    int d = idx >> 3, c8 = (idx & 7) * 8;
    union { unsigned short u[8]; bf16x8 v; } o;
#pragma unroll
    for (int j = 0; j < 8; j++) o.u[j] = Vt_s[(c8 + j) * 132 + d];
    *(bf16x8*)(v_t + ((size_t)bh * 128 + d) * 2048 + n0 + c8) = o.v;
  }
}

// ---------- NT GEMM: 4-deep pipelined, counted vmcnt, XCD-swizzled ----------
template <int MODE>
__global__ __launch_bounds__(256) void gemm_bt(const unsigned short* __restrict__ A,
                                               const unsigned short* __restrict__ B,
                                               float* __restrict__ Cf,
                                               unsigned short* __restrict__ Cb,
                                               int K, int ldc) {
  __shared__ unsigned short As[4][128 * 32];
  __shared__ unsigned short Bs[4][128 * 32];
  int tid = threadIdx.x;
  int wave = tid >> 6, lane = tid & 63, l15 = lane & 15, lg = lane >> 4;
  int wr = wave >> 1, wc = wave & 1;
  int lin = blockIdx.y * gridDim.x + blockIdx.x;
  int cpx = (gridDim.x * gridDim.y) >> 3;
  int swz = (lin & 7) * cpx + (lin >> 3);
  int bx = swz % gridDim.x, by = swz / gridDim.x;
  int row0 = by * 128, col0 = bx * 128;
  f32x4 acc[4][4];
#pragma unroll
  for (int m = 0; m < 4; m++)
#pragma unroll
    for (int n = 0; n < 4; n++) acc[m][n] = (f32x4){0.f, 0.f, 0.f, 0.f};

  // stage tile kti (BK=32) into buffer bs: 4 loads/thread (2 A + 2 B)
#define STAGE_T(kti, bs)                                                                           \
  {                                                                                                \
    int k0_ = (kti) * 32;                                                                          \
    _Pragma("unroll") for (int c = 0; c < 2; c++) {                                                \
      int chunk = c * 256 + tid;                                                                   \
      int r = chunk >> 2, kk = (chunk & 3) * 8;                                                    \
      __builtin_amdgcn_global_load_lds(                                                            \
          (const __attribute__((address_space(1))) void*)(A + (size_t)(row0 + r) * K + k0_ + kk),  \
          (__attribute__((address_space(3))) void*)(&As[bs][((size_t)c * 256 + wave * 64) * 8]),   \
          16, 0, 0);                                                                               \
      __builtin_amdgcn_global_load_lds(                                                            \
          (const __attribute__((address_space(1))) void*)(B + (size_t)(col0 + r) * K + k0_ + kk),  \
          (__attribute__((address_space(3))) void*)(&Bs[bs][((size_t)c * 256 + wave * 64) * 8]),   \
          16, 0, 0);                                                                               \
    }                                                                                              \
  }

  int nt = K >> 5;
  STAGE_T(0, 0);
  STAGE_T(1, 1);
  STAGE_T(2, 2);

  for (int t = 0; t < nt; ++t) {
    int cur = t & 3;
    int ahead = nt - 1 - t;
    if (ahead > 2) ahead = 2;
    // wait until tile t's 4 loads (oldest) are complete; keep younger tiles in flight
    if (ahead == 2) asm volatile("s_waitcnt vmcnt(8)" ::: "memory");
    else if (ahead == 1) asm volatile("s_waitcnt vmcnt(4)" ::: "memory");
    else asm volatile("s_waitcnt vmcnt(0)" ::: "memory");
    __builtin_amdgcn_sched_barrier(0);
    __builtin_amdgcn_s_barrier();
    __builtin_amdgcn_sched_barrier(0);
    if (t + 3 < nt) STAGE_T(t + 3, (t + 3) & 3);
    bf16x8 af[4], bfr[4];
#pragma unroll
    for (int m = 0; m < 4; m++)
      af[m] = *(const bf16x8*)&As[cur][(wr * 64 + m * 16 + l15) * 32 + lg * 8];
#pragma unroll
    for (int n = 0; n < 4; n++)
      bfr[n] = *(const bf16x8*)&Bs[cur][(wc * 64 + n * 16 + l15) * 32 + lg * 8];
    __builtin_amdgcn_s_setprio(1);
#pragma unroll
    for (int m = 0; m < 4; m++)
#pragma unroll
      for (int n = 0; n < 4; n++) acc[m][n] = MFMA16(af[m], bfr[n], acc[m][n]);
    __builtin_amdgcn_s_setprio(0);
  }
#undef STAGE_T

#pragma unroll
  for (int m = 0; m < 4; m++) {
    int row_b = row0 + wr * 64 + m * 16 + lg * 4;
#pragma unroll
    for (int n = 0; n < 4; n++) {
      int col = col0 + wc * 64 + n * 16 + l15;
#pragma unroll
      for (int j = 0; j < 4; j++) {
        int row = row_b + j;
        if (MODE == 0) {
          Cf[(size_t)row * ldc + col] = acc[m][n][j];
        } else {
          int b = row >> 11, nn = row & 2047, h = col >> 7, d = col & 127;
          Cb[(((size_t)b * 16 + h) * 2048 + nn) * 128 + d] = f2bf(acc[m][n][j]);
        }
      }
    }
  }
}

// ---------- flash attention v4: fused Q-rope, exp2 domain, MFMA row-sum, defer-max ----------
__global__ __launch_bounds__(256, 2) void flash_attn(const unsigned short* __restrict__ q_r,
                                                     const unsigned short* __restrict__ k_r,
                                                     const unsigned short* __restrict__ v_t,
                                                     const float2* __restrict__ cs,
                                                     unsigned short* __restrict__ o) {
  int lin = blockIdx.y * 16 + blockIdx.x;
  int swz = (lin & 7) * 64 + (lin >> 3);
  int bx = swz & 15, bh = swz >> 4;
  const unsigned short* Kg = k_r + (size_t)bh * 2048 * 128;
  const unsigned short* Vtg = v_t + (size_t)bh * 128 * 2048;
  __shared__ unsigned short Ks[2][64 * 128];
  __shared__ unsigned short VTs[2][128 * 64];
  __shared__ unsigned short Ps[4][16 * 72];
  int tid = threadIdx.x, wave = tid >> 6, lane = tid & 63, l15 = lane & 15, lg = lane >> 4;
  int sw = (l15 & 7) * 8;
  int b = bh >> 4, h = bh & 15;

  union { unsigned short u[8]; bf16x8 v; } onesu;
#pragma unroll
  for (int j = 0; j < 8; j++) onesu.u[j] = 0x3F80;
  const bf16x8 ones = onesu.v;

  int qtA = bx, qtB = 31 - bx;
  int qt = qtA;

  bf16x8 qf[4];
#define LOAD_Q()                                                                                   \
  {                                                                                                \
    const unsigned short* Qg = q_r + ((size_t)bh * 2048 + qt * 64) * 128;                          \
    int n = qt * 64 + wave * 16 + l15;                                                             \
    union { unsigned short u[8]; bf16x8 v; } r0, r1, r2, r3;                                       \
    r0.v = *(const bf16x8*)(Qg + (wave * 16 + l15) * 128 + 0 * 32 + lg * 8);                       \
    r1.v = *(const bf16x8*)(Qg + (wave * 16 + l15) * 128 + 1 * 32 + lg * 8);                       \
    r2.v = *(const bf16x8*)(Qg + (wave * 16 + l15) * 128 + 2 * 32 + lg * 8);                       \
    r3.v = *(const bf16x8*)(Qg + (wave * 16 + l15) * 128 + 3 * 32 + lg * 8);                       \
    union { unsigned short u[8]; bf16x8 v; } o0, o1, o2, o3;                                       \
    _Pragma("unroll") for (int j = 0; j < 8; j++) {                                                \
      float2 c0 = cs[(n << 6) + 0 * 32 + lg * 8 + j];                                              \
      float t1 = bf2f(r0.u[j]), t2 = bf2f(r2.u[j]);                                                \
      o0.u[j] = f2bf(t1 * c0.x - t2 * c0.y);                                                       \
      o2.u[j] = f2bf(t2 * c0.x + t1 * c0.y);                                                       \
      float2 c1 = cs[(n << 6) + 1 * 32 + lg * 8 + j];                                              \
      float s1 = bf2f(r1.u[j]), s2 = bf2f(r3.u[j]);                                                \
      o1.u[j] = f2bf(s1 * c1.x - s2 * c1.y);                                                       \
      o3.u[j] = f2bf(s2 * c1.x + s1 * c1.y);                                                       \
    }                                                                                              \
    qf[0] = o0.v; qf[1] = o1.v; qf[2] = o2.v; qf[3] = o3.v;                                        \
  }

  LOAD_Q();

  float m_r[4], l_r[4];
  f32x4 oacc[8];
#pragma unroll
  for (int j = 0; j < 4; j++) { m_r[j] = -INFINITY; l_r[j] = 0.f; }
#pragma unroll
  for (int db = 0; db < 8; db++) oacc[db] = (f32x4){0.f, 0.f, 0.f, 0.f};

  const float kscale = 0.12753102f;  // (1/sqrt(128)) * log2(e)
  const float THR = 11.0f;

#define STAGE(kt, bsel)                                                                           \
  {                                                                                               \
    int kti = (kt);                                                                               \
    int bs = (bsel);                                                                              \
    _Pragma("unroll") for (int c = 0; c < 4; c++) {                                               \
      int s = c * 256 + tid;                                                                      \
      int kr = s >> 4, kc = ((s & 15) ^ (kr & 7)) * 8;                                            \
      __builtin_amdgcn_global_load_lds(                                                           \
          (const __attribute__((address_space(1))) void*)(Kg + (size_t)(kti * 64 + kr) * 128 + kc),\
          (__attribute__((address_space(3))) void*)(&Ks[bs][(c * 256 + wave * 64) * 8]), 16, 0, 0);\
      int vr = s >> 3, vc = ((s & 7) ^ (vr & 7)) * 8;                                             \
      __builtin_amdgcn_global_load_lds(                                                           \
          (const __attribute__((address_space(1))) void*)(Vtg + (size_t)vr * 2048 + kti * 64 + vc),\
          (__attribute__((address_space(3))) void*)(&VTs[bs][(c * 256 + wave * 64) * 8]), 16, 0, 0);\
    }                                                                                             \
  }

  STAGE(0, 0);
  __syncthreads();

  for (int s = 0; s < 33; ++s) {
    int nb = s & 1;
    if (s + 1 < 33) {
      int nk = (s + 1 <= qtA) ? (s + 1) : (s + 1 - (qtA + 1));
      STAGE(nk, nb ^ 1);
    }
    int kt = (s <= qtA) ? s : (s - (qtA + 1));
    bool diag = (s == qtA) || (s == 32);
    int qrow0 = qt * 64 + wave * 16 + lg * 4;

    f32x4 sc[4];
#pragma unroll
    for (int cb = 0; cb < 4; cb++) sc[cb] = (f32x4){0.f, 0.f, 0.f, 0.f};
    __builtin_amdgcn_s_setprio(1);
#pragma unroll
    for (int kk = 0; kk < 4; kk++) {
#pragma unroll
      for (int cb = 0; cb < 4; cb++) {
        bf16x8 kf = *(const bf16x8*)&Ks[nb][(cb * 16 + l15) * 128 + ((kk * 32 + lg * 8) ^ sw)];
        sc[cb] = MFMA16(qf[kk], kf, sc[cb]);
      }
    }
    __builtin_amdgcn_s_setprio(0);
    if (diag) {
#pragma unroll
      for (int cb = 0; cb < 4; cb++) {
        int col = kt * 64 + cb * 16 + l15;
#pragma unroll
        for (int j = 0; j < 4; j++) {
          float v = sc[cb][j] * kscale;
          if (col > qrow0 + j) v = -INFINITY;
          sc[cb][j] = v;
        }
      }
    } else {
#pragma unroll
      for (int cb = 0; cb < 4; cb++)
#pragma unroll
        for (int j = 0; j < 4; j++) sc[cb][j] *= kscale;
    }
    float pm[4];
#pragma unroll
    for (int j = 0; j < 4; j++)
      pm[j] = fmaxf(fmaxf(sc[0][j], sc[1][j]), fmaxf(sc[2][j], sc[3][j]));
    bool grow = !__all((pm[0] <= m_r[0] + THR) & (pm[1] <= m_r[1] + THR) &
                       (pm[2] <= m_r[2] + THR) & (pm[3] <= m_r[3] + THR));
    if (grow) {
#pragma unroll
      for (int off = 1; off < 16; off <<= 1) {
#pragma unroll
        for (int j = 0; j < 4; j++) pm[j] = fmaxf(pm[j], __shfl_xor(pm[j], off));
      }
#pragma unroll
      for (int j = 0; j < 4; j++) {
        float mn = fmaxf(m_r[j], pm[j]);
        float corr = fast_exp2(m_r[j] - mn);
        m_r[j] = mn;
        l_r[j] *= corr;
#pragma unroll
        for (int db = 0; db < 8; db++) oacc[db][j] *= corr;
      }
    }
#pragma unroll
    for (int cb = 0; cb < 4; cb++)
#pragma unroll
      for (int j = 0; j < 4; j++)
        Ps[wave][(lg * 4 + j) * 72 + cb * 16 + l15] = f2bf(fast_exp2(sc[cb][j] - m_r[j]));
    f32x4 sacc = (f32x4){0.f, 0.f, 0.f, 0.f};
    __builtin_amdgcn_s_setprio(1);
#pragma unroll
    for (int kc = 0; kc < 2; kc++) {
      bf16x8 pa = *(const bf16x8*)&Ps[wave][l15 * 72 + kc * 32 + lg * 8];
      sacc = MFMA16(pa, ones, sacc);
#pragma unroll
      for (int db = 0; db < 8; db++) {
        bf16x8 vb = *(const bf16x8*)&VTs[nb][(db * 16 + l15) * 64 + ((kc * 32 + lg * 8) ^ sw)];
        oacc[db] = MFMA16(pa, vb, oacc[db]);
      }
    }
    __builtin_amdgcn_s_setprio(0);
#pragma unroll
    for (int j = 0; j < 4; j++) l_r[j] += sacc[j];
    __syncthreads();

    if (s == qtA) {
      int qrow_e = qt * 64 + wave * 16 + lg * 4;
#pragma unroll
      for (int db = 0; db < 8; db++) {
        int d = db * 16 + l15;
#pragma unroll
        for (int j = 0; j < 4; j++) {
          float val = oacc[db][j] / l_r[j];
          o[((size_t)(b * 2048 + qrow_e + j)) * 2048 + h * 128 + d] = f2bf(val);
        }
      }
      qt = qtB;
      LOAD_Q();
#pragma unroll
      for (int j = 0; j < 4; j++) { m_r[j] = -INFINITY; l_r[j] = 0.f; }
#pragma unroll
      for (int db = 0; db < 8; db++) oacc[db] = (f32x4){0.f, 0.f, 0.f, 0.f};
    }
  }
  int qrow_e = qt * 64 + wave * 16 + lg * 4;
#pragma unroll
  for (int db = 0; db < 8; db++) {
    int d = db * 16 + l15;
#pragma unroll
    for (int j = 0; j < 4; j++) {
      float val = oacc[db][j] / l_r[j];
      o[((size_t)(b * 2048 + qrow_e + j)) * 2048 + h * 128 + d] = f2bf(val);
    }
  }
#undef STAGE
#undef LOAD_Q
}

// ---------- host launch ----------
extern "C" void kernel_launch(void* const* d_in, const int* in_sizes, int n_in,
                              void* d_out, int out_size, void* d_ws, size_t ws_size,
                              hipStream_t stream) {
  (void)in_sizes; (void)n_in; (void)out_size; (void)ws_size;
  const float* x    = (const float*)d_in[0];
  const float* Wq   = (const float*)d_in[1];
  const float* Wkv  = (const float*)d_in[2];
  const float* Wkvh = (const float*)d_in[3];
  const float* Wg   = (const float*)d_in[4];
  const float* Wout = (const float*)d_in[5];
  float* out = (float*)d_out;

  char* ws = (char*)d_ws;
  size_t off = 0;
  auto alloc = [&](size_t bytes) -> void* {
    void* p = ws + off;
    off += (bytes + 255) & ~(size_t)255;
    return p;
  };
  unsigned short* x_bf    = (unsigned short*)alloc(4096ull * 2048 * 2);
  unsigned short* wq_bf   = (unsigned short*)alloc(2048ull * 2048 * 2);
  unsigned short* wout_bf = (unsigned short*)alloc(2048ull * 2048 * 2);
  unsigned short* wsm_bf  = (unsigned short*)alloc(384ull * 2048 * 2);
  unsigned short* q_r     = (unsigned short*)alloc(4096ull * 2048 * 2);
  unsigned short* k_r     = (unsigned short*)alloc(4096ull * 2048 * 2);
  unsigned short* o_bf    = (unsigned short*)alloc(4096ull * 2048 * 2);
  float* small_out        = (float*)alloc(4096ull * 384 * 4);
  float* lsg_t            = (float*)alloc(64ull * 2048 * 4);
  float* khvh             = (float*)alloc(4096ull * 32 * 4);
  float2* cs              = (float2*)alloc(2048ull * 64 * 8);
  float* wgt              = (float*)alloc(2048ull * 32 * 4);
  unsigned short* v_t     = x_bf;  // x_bf dead after the q/small GEMMs

  prep<<<9344, 256, 0, stream>>>(x, Wq, Wout, Wkv, Wkvh, Wg, x_bf, wq_bf, wout_bf, wsm_bf, cs, wgt);
  gproj<<<512, 256, 0, stream>>>(x, wgt, lsg_t);
  gemm_bt<0><<<dim3(3, 32), 256, 0, stream>>>(x_bf, wsm_bf, small_out, nullptr, 2048, 384);
  gemm_bt<2><<<dim3(16, 32), 256, 0, stream>>>(x_bf, wq_bf, nullptr, q_r, 2048, 2048);
  scan_kernel<<<64, 256, 0, stream>>>(lsg_t, small_out, khvh);
  build_kv2<<<dim3(32, 32), 256, 0, stream>>>(small_out, khvh, cs, k_r, v_t);
  flash_attn<<<dim3(16, 32), 256, 0, stream>>>(q_r, k_r, v_t, cs, o_bf);
  gemm_bt<0><<<dim3(16, 32), 256, 0, stream>>>(o_bf, wout_bf, out, nullptr, 2048, 2048);
}

// Round 8
// 301.909 us; speedup vs baseline: 1.8040x; 1.0049x over previous
//
#include <hip/hip_runtime.h>
#include <hip/hip_bf16.h>
#include <math.h>

// ---------- types ----------
typedef __attribute__((ext_vector_type(8))) short bf16x8;
typedef __attribute__((ext_vector_type(4))) float f32x4;

#define MFMA16(a, b, c) __builtin_amdgcn_mfma_f32_16x16x32_bf16((a), (b), (c), 0, 0, 0)

static __device__ __forceinline__ float fast_exp2(float x) { return __builtin_amdgcn_exp2f(x); }

static __device__ __forceinline__ unsigned short f2bf(float f) {
  __hip_bfloat16 h = __float2bfloat16(f);
  unsigned short u;
  __builtin_memcpy(&u, &h, 2);
  return u;
}
static __device__ __forceinline__ float bf2f(unsigned short u) {
  unsigned int x = ((unsigned int)u) << 16;
  float f;
  __builtin_memcpy(&f, &x, 4);
  return f;
}

// ---------- merged prep: casts + wsmall + rope table + wg transpose ----------
static __device__ __forceinline__ void cast8(const float* __restrict__ src,
                                             unsigned short* __restrict__ dst, int blk, int tid) {
  int i = (blk * 256 + tid) * 8;
  float4 a = *(const float4*)(src + i);
  float4 b = *(const float4*)(src + i + 4);
  union { unsigned short u[8]; bf16x8 v; } o;
  o.u[0] = f2bf(a.x); o.u[1] = f2bf(a.y); o.u[2] = f2bf(a.z); o.u[3] = f2bf(a.w);
  o.u[4] = f2bf(b.x); o.u[5] = f2bf(b.y); o.u[6] = f2bf(b.z); o.u[7] = f2bf(b.w);
  *(bf16x8*)(dst + i) = o.v;
}

__global__ __launch_bounds__(256) void prep(const float* __restrict__ x, const float* __restrict__ Wq,
                                            const float* __restrict__ Wout, const float* __restrict__ Wkv,
                                            const float* __restrict__ Wkvh, const float* __restrict__ Wg,
                                            unsigned short* __restrict__ x_bf, unsigned short* __restrict__ wq_bf,
                                            unsigned short* __restrict__ wout_bf, unsigned short* __restrict__ wsm_bf,
                                            float2* __restrict__ cs, float* __restrict__ wgt) {
  int bid = blockIdx.x, tid = threadIdx.x;
  if (bid < 4096) {
    cast8(x, x_bf, bid, tid);
  } else if (bid < 6144) {
    cast8(Wq, wq_bf, bid - 4096, tid);
  } else if (bid < 8192) {
    cast8(Wout, wout_bf, bid - 6144, tid);
  } else if (bid < 8576) {
    int row = bid - 8192;
    int c = tid * 8;
    const float* src = nullptr;
    if (row < 256) src = Wkv + (size_t)row * 2048;
    else if (row < 288) src = Wkvh + (size_t)(row - 256) * 2048;
    union { unsigned short u[8]; bf16x8 v; } o;
    if (src) {
      float4 a = *(const float4*)(src + c);
      float4 b = *(const float4*)(src + c + 4);
      o.u[0] = f2bf(a.x); o.u[1] = f2bf(a.y); o.u[2] = f2bf(a.z); o.u[3] = f2bf(a.w);
      o.u[4] = f2bf(b.x); o.u[5] = f2bf(b.y); o.u[6] = f2bf(b.z); o.u[7] = f2bf(b.w);
    } else {
      for (int j = 0; j < 8; j++) o.u[j] = 0;
    }
    *(bf16x8*)(wsm_bf + (size_t)row * 2048 + c) = o.v;
  } else if (bid < 9088) {
    int i = (bid - 8576) * 256 + tid;
    int f = i & 63, n = i >> 6;
    float inv = powf(10000.0f, -(float)(2 * f) / 128.0f);
    float ang = (float)n * inv;
    cs[i] = make_float2(cosf(ang), sinf(ang));
  } else {
    int i = (bid - 9088) * 256 + tid;
    int oc = i >> 11, k = i & 2047;
    wgt[(size_t)k * 32 + oc] = Wg[i];
  }
}

// ---------- lsg_t[b][ch][n] = log_sigmoid(x @ Wg^T), transposed write ----------
__global__ __launch_bounds__(256) void gproj(const float* __restrict__ x, const float* __restrict__ Wgt,
                                             float* __restrict__ lsg_t) {
  int tid = blockIdx.x * 256 + threadIdx.x;  // 4096*32
  int tok = tid >> 5, oc = tid & 31;
  const float* xr = x + (size_t)tok * 2048;
  float acc = 0.f;
  for (int k = 0; k < 2048; k += 4) {
    float4 a = *(const float4*)(xr + k);
    acc += a.x * Wgt[(size_t)k * 32 + oc] + a.y * Wgt[(size_t)(k + 1) * 32 + oc] +
           a.z * Wgt[(size_t)(k + 2) * 32 + oc] + a.w * Wgt[(size_t)(k + 3) * 32 + oc];
  }
  float ls = (acc >= 0.f) ? -log1pf(expf(-acc)) : acc - log1pf(expf(acc));
  int b = tok >> 11, n = tok & 2047;
  lsg_t[((size_t)(b * 32 + oc)) * 2048 + n] = ls;
}

// ---------- scan v3: 64 blocks (b,ch), 256 thr x 8 toks, shfl wave-scan ----------
__global__ __launch_bounds__(256) void scan_kernel(const float* __restrict__ lsg_t,
                                                   const float* __restrict__ so,
                                                   float* __restrict__ khvh) {
  int b = blockIdx.x >> 5, ch = blockIdx.x & 31;
  int t = threadIdx.x, lane = t & 63, wv = t >> 6;
  const float* L = lsg_t + ((size_t)(b * 32 + ch)) * 2048 + t * 8;
  float ls[8], v[8];
  float4 a = *(const float4*)L, c = *(const float4*)(L + 4);
  ls[0] = a.x; ls[1] = a.y; ls[2] = a.z; ls[3] = a.w;
  ls[4] = c.x; ls[5] = c.y; ls[6] = c.z; ls[7] = c.w;
  const float* V = so + ((size_t)(b * 2048 + t * 8)) * 384 + 256 + ch;
#pragma unroll
  for (int j = 0; j < 8; j++) v[j] = V[(size_t)j * 384];
  float run = 0.f;
#pragma unroll
  for (int j = 0; j < 8; j++) run += ls[j];
  float incl = run;
#pragma unroll
  for (int off = 1; off < 64; off <<= 1) {
    float nv = __shfl_up(incl, off);
    if (lane >= off) incl += nv;
  }
  __shared__ float ws[2][4];
  if (lane == 63) ws[0][wv] = incl;
  __syncthreads();
  float wbase = 0.f;
#pragma unroll
  for (int w = 0; w < 4; w++) wbase += (w < wv) ? ws[0][w] : 0.f;
  float baseA = wbase + incl - run;
  float lf = baseA, s = 0.f;
#pragma unroll
  for (int j = 0; j < 8; j++) { s += v[j] * __expf(lf); lf += ls[j]; }
  float incl2 = s;
#pragma unroll
  for (int off = 1; off < 64; off <<= 1) {
    float nv = __shfl_up(incl2, off);
    if (lane >= off) incl2 += nv;
  }
  if (lane == 63) ws[1][wv] = incl2;
  __syncthreads();
  float wbase2 = 0.f;
#pragma unroll
  for (int w = 0; w < 4; w++) wbase2 += (w < wv) ? ws[1][w] : 0.f;
  float base2 = wbase2 + incl2 - s;
  lf = baseA; s = base2;
  float* O = khvh + ((size_t)(b * 2048 + t * 8)) * 32 + ch;
#pragma unroll
  for (int j = 0; j < 8; j++) { s += v[j] * __expf(lf); lf += ls[j]; O[(size_t)j * 32] = s; }
}

// ---------- build_kv2: merged k_r build (+rope) and v_t transposed build ----------
__global__ __launch_bounds__(256) void build_kv2(const float* __restrict__ so,
                                                 const float* __restrict__ khvh,
                                                 const float2* __restrict__ cs,
                                                 unsigned short* __restrict__ k_r,
                                                 unsigned short* __restrict__ v_t) {
  int ntb = blockIdx.x, bh = blockIdx.y;
  int b = bh >> 4, h = bh & 15;
  int tok0 = b * 2048 + ntb * 64;
  int n0 = ntb * 64;
  __shared__ float khs[64], vhs[64];
  __shared__ unsigned short Vt_s[64 * 132];
  int t = threadIdx.x;
  if (t < 64) {
    khs[t] = khvh[(size_t)(tok0 + t) * 32 + h];
    vhs[t] = khvh[(size_t)(tok0 + t) * 32 + 16 + h];
  }
  __syncthreads();
#pragma unroll
  for (int c = 0; c < 4; c++) {
    int idx = c * 256 + t;
    int r = idx >> 4, q4 = (idx & 15) * 4;
    const float* sop = so + (size_t)(tok0 + r) * 384;
    float4 k1 = *(const float4*)(sop + q4);
    float4 k2 = *(const float4*)(sop + 64 + q4);
    float kh = khs[r];
    int n = n0 + r;
    union { unsigned short u[4]; uint2 v2; } o1, o2;
#pragma unroll
    for (int j = 0; j < 4; j++) {
      float2 cc = cs[(n << 6) + q4 + j];
      float av = ((const float*)&k1)[j], bv = ((const float*)&k2)[j];
      o1.u[j] = f2bf((av * cc.x - bv * cc.y) * kh);
      o2.u[j] = f2bf((bv * cc.x + av * cc.y) * kh);
    }
    size_t off = ((size_t)bh * 2048 + n) * 128 + q4;
    *(uint2*)(k_r + off) = o1.v2;
    *(uint2*)(k_r + off + 64) = o2.v2;
  }
#pragma unroll
  for (int c = 0; c < 8; c++) {
    int idx = c * 256 + t;
    int r = idx >> 5, d4 = (idx & 31) * 4;
    const float* sop = so + (size_t)(tok0 + r) * 384 + 128;
    float4 v = *(const float4*)(sop + d4);
    float vh = vhs[r];
    union { unsigned short u[4]; uint2 v2; } ov;
#pragma unroll
    for (int j = 0; j < 4; j++) ov.u[j] = f2bf(((const float*)&v)[j] * vh);
    *(uint2*)&Vt_s[r * 132 + d4] = ov.v2;
  }
  __syncthreads();
#pragma unroll
  for (int c = 0; c < 4; c++) {
    int idx = c * 256 + t;
    int d = idx >> 3, c8 = (idx & 7) * 8;
    union { unsigned short u[8]; bf16x8 v; } o;
#pragma unroll
    for (int j = 0; j < 8; j++) o.u[j] = Vt_s[(c8 + j) * 132 + d];
    *(bf16x8*)(v_t + ((size_t)bh * 128 + d) * 2048 + n0 + c8) = o.v;
  }
}

// ---------- NT GEMM: 4-deep pipelined, counted vmcnt, T2 LDS swizzle, XCD swizzle ----------
// MODE 0: C fp32 (ldc).  MODE 1: merged q+small — cols<2048 scatter bf16 to q_r, cols>=2048 fp32 small_out.
template <int MODE>
__global__ __launch_bounds__(256) void gemm_bt(const unsigned short* __restrict__ A,
                                               const unsigned short* __restrict__ B,
                                               float* __restrict__ Cf,
                                               unsigned short* __restrict__ Cb,
                                               int K, int ldc) {
  __shared__ unsigned short As[4][128 * 32];
  __shared__ unsigned short Bs[4][128 * 32];
  int tid = threadIdx.x;
  int wave = tid >> 6, lane = tid & 63, l15 = lane & 15, lg = lane >> 4;
  int wr = wave >> 1, wc = wave & 1;
  int lin = blockIdx.y * gridDim.x + blockIdx.x;
  int cpx = (gridDim.x * gridDim.y) >> 3;
  int swz = (lin & 7) * cpx + (lin >> 3);
  int bx = swz % gridDim.x, by = swz / gridDim.x;
  int row0 = by * 128, col0 = bx * 128;
  // T2 read-side xor per thread (slot = lg ^ sxor)
  int sxor = (l15 & 3) ^ (l15 >> 2);
  f32x4 acc[4][4];
#pragma unroll
  for (int m = 0; m < 4; m++)
#pragma unroll
    for (int n = 0; n < 4; n++) acc[m][n] = (f32x4){0.f, 0.f, 0.f, 0.f};

  // stage tile kti (BK=32) into buffer bs; source col pre-swizzled (T2)
#define STAGE_T(kti, bs)                                                                           \
  {                                                                                                \
    int k0_ = (kti) * 32;                                                                          \
    _Pragma("unroll") for (int c = 0; c < 2; c++) {                                                \
      int chunk = c * 256 + tid;                                                                   \
      int r = chunk >> 2, sl = chunk & 3;                                                          \
      int kk = (sl ^ (r & 3) ^ ((r >> 2) & 3)) * 8;                                                \
      __builtin_amdgcn_global_load_lds(                                                            \
          (const __attribute__((address_space(1))) void*)(A + (size_t)(row0 + r) * K + k0_ + kk),  \
          (__attribute__((address_space(3))) void*)(&As[bs][(size_t)chunk * 8]), 16, 0, 0);        \
      __builtin_amdgcn_global_load_lds(                                                            \
          (const __attribute__((address_space(1))) void*)(B + (size_t)(col0 + r) * K + k0_ + kk),  \
          (__attribute__((address_space(3))) void*)(&Bs[bs][(size_t)chunk * 8]), 16, 0, 0);        \
    }                                                                                              \
  }

  int nt = K >> 5;
  STAGE_T(0, 0);
  STAGE_T(1, 1);
  STAGE_T(2, 2);

  for (int t = 0; t < nt; ++t) {
    int cur = t & 3;
    int ahead = nt - 1 - t;
    if (ahead > 2) ahead = 2;
    if (ahead == 2) asm volatile("s_waitcnt vmcnt(8)" ::: "memory");
    else if (ahead == 1) asm volatile("s_waitcnt vmcnt(4)" ::: "memory");
    else asm volatile("s_waitcnt vmcnt(0)" ::: "memory");
    __builtin_amdgcn_sched_barrier(0);
    __builtin_amdgcn_s_barrier();
    __builtin_amdgcn_sched_barrier(0);
    if (t + 3 < nt) STAGE_T(t + 3, (t + 3) & 3);
    bf16x8 af[4], bfr[4];
#pragma unroll
    for (int m = 0; m < 4; m++) {
      int R = wr * 64 + m * 16 + l15;
      af[m] = *(const bf16x8*)&As[cur][R * 32 + ((lg ^ sxor)) * 8];
    }
#pragma unroll
    for (int n = 0; n < 4; n++) {
      int R = wc * 64 + n * 16 + l15;
      bfr[n] = *(const bf16x8*)&Bs[cur][R * 32 + ((lg ^ sxor)) * 8];
    }
    __builtin_amdgcn_s_setprio(1);
#pragma unroll
    for (int m = 0; m < 4; m++)
#pragma unroll
      for (int n = 0; n < 4; n++) acc[m][n] = MFMA16(af[m], bfr[n], acc[m][n]);
    __builtin_amdgcn_s_setprio(0);
  }
#undef STAGE_T

  if (MODE == 0 || col0 >= 2048) {
#pragma unroll
    for (int m = 0; m < 4; m++) {
      int row_b = row0 + wr * 64 + m * 16 + lg * 4;
#pragma unroll
      for (int n = 0; n < 4; n++) {
        int col = col0 + wc * 64 + n * 16 + l15;
        int cw = (MODE == 0) ? col : (col - 2048);
#pragma unroll
        for (int j = 0; j < 4; j++) {
          Cf[(size_t)(row_b + j) * ldc + cw] = acc[m][n][j];
        }
      }
    }
  } else {
#pragma unroll
    for (int m = 0; m < 4; m++) {
      int row_b = row0 + wr * 64 + m * 16 + lg * 4;
#pragma unroll
      for (int n = 0; n < 4; n++) {
        int col = col0 + wc * 64 + n * 16 + l15;
        int h = col >> 7, d = col & 127;
#pragma unroll
        for (int j = 0; j < 4; j++) {
          int row = row_b + j;
          int b = row >> 11, nn = row & 2047;
          Cb[(((size_t)b * 16 + h) * 2048 + nn) * 128 + d] = f2bf(acc[m][n][j]);
        }
      }
    }
  }
}

// ---------- flash attention v4.1: Ps stride 80 (conflict-free writes) ----------
__global__ __launch_bounds__(256, 2) void flash_attn(const unsigned short* __restrict__ q_r,
                                                     const unsigned short* __restrict__ k_r,
                                                     const unsigned short* __restrict__ v_t,
                                                     const float2* __restrict__ cs,
                                                     unsigned short* __restrict__ o) {
  int lin = blockIdx.y * 16 + blockIdx.x;
  int swz = (lin & 7) * 64 + (lin >> 3);
  int bx = swz & 15, bh = swz >> 4;
  const unsigned short* Kg = k_r + (size_t)bh * 2048 * 128;
  const unsigned short* Vtg = v_t + (size_t)bh * 128 * 2048;
  __shared__ unsigned short Ks[2][64 * 128];
  __shared__ unsigned short VTs[2][128 * 64];
  __shared__ unsigned short Ps[4][16 * 80];
  int tid = threadIdx.x, wave = tid >> 6, lane = tid & 63, l15 = lane & 15, lg = lane >> 4;
  int sw = (l15 & 7) * 8;
  int b = bh >> 4, h = bh & 15;

  union { unsigned short u[8]; bf16x8 v; } onesu;
#pragma unroll
  for (int j = 0; j < 8; j++) onesu.u[j] = 0x3F80;
  const bf16x8 ones = onesu.v;

  int qtA = bx, qtB = 31 - bx;
  int qt = qtA;

  bf16x8 qf[4];
#define LOAD_Q()                                                                                   \
  {                                                                                                \
    const unsigned short* Qg = q_r + ((size_t)bh * 2048 + qt * 64) * 128;                          \
    int n = qt * 64 + wave * 16 + l15;                                                             \
    union { unsigned short u[8]; bf16x8 v; } r0, r1, r2, r3;                                       \
    r0.v = *(const bf16x8*)(Qg + (wave * 16 + l15) * 128 + 0 * 32 + lg * 8);                       \
    r1.v = *(const bf16x8*)(Qg + (wave * 16 + l15) * 128 + 1 * 32 + lg * 8);                       \
    r2.v = *(const bf16x8*)(Qg + (wave * 16 + l15) * 128 + 2 * 32 + lg * 8);                       \
    r3.v = *(const bf16x8*)(Qg + (wave * 16 + l15) * 128 + 3 * 32 + lg * 8);                       \
    union { unsigned short u[8]; bf16x8 v; } o0, o1, o2, o3;                                       \
    _Pragma("unroll") for (int j = 0; j < 8; j++) {                                                \
      float2 c0 = cs[(n << 6) + 0 * 32 + lg * 8 + j];                                              \
      float t1 = bf2f(r0.u[j]), t2 = bf2f(r2.u[j]);                                                \
      o0.u[j] = f2bf(t1 * c0.x - t2 * c0.y);                                                       \
      o2.u[j] = f2bf(t2 * c0.x + t1 * c0.y);                                                       \
      float2 c1 = cs[(n << 6) + 1 * 32 + lg * 8 + j];                                              \
      float s1 = bf2f(r1.u[j]), s2 = bf2f(r3.u[j]);                                                \
      o1.u[j] = f2bf(s1 * c1.x - s2 * c1.y);                                                       \
      o3.u[j] = f2bf(s2 * c1.x + s1 * c1.y);                                                       \
    }                                                                                              \
    qf[0] = o0.v; qf[1] = o1.v; qf[2] = o2.v; qf[3] = o3.v;                                        \
  }

  LOAD_Q();

  float m_r[4], l_r[4];
  f32x4 oacc[8];
#pragma unroll
  for (int j = 0; j < 4; j++) { m_r[j] = -INFINITY; l_r[j] = 0.f; }
#pragma unroll
  for (int db = 0; db < 8; db++) oacc[db] = (f32x4){0.f, 0.f, 0.f, 0.f};

  const float kscale = 0.12753102f;  // (1/sqrt(128)) * log2(e)
  const float THR = 11.0f;

#define STAGE(kt, bsel)                                                                           \
  {                                                                                               \
    int kti = (kt);                                                                               \
    int bs = (bsel);                                                                              \
    _Pragma("unroll") for (int c = 0; c < 4; c++) {                                               \
      int s = c * 256 + tid;                                                                      \
      int kr = s >> 4, kc = ((s & 15) ^ (kr & 7)) * 8;                                            \
      __builtin_amdgcn_global_load_lds(                                                           \
          (const __attribute__((address_space(1))) void*)(Kg + (size_t)(kti * 64 + kr) * 128 + kc),\
          (__attribute__((address_space(3))) void*)(&Ks[bs][(c * 256 + wave * 64) * 8]), 16, 0, 0);\
      int vr = s >> 3, vc = ((s & 7) ^ (vr & 7)) * 8;                                             \
      __builtin_amdgcn_global_load_lds(                                                           \
          (const __attribute__((address_space(1))) void*)(Vtg + (size_t)vr * 2048 + kti * 64 + vc),\
          (__attribute__((address_space(3))) void*)(&VTs[bs][(c * 256 + wave * 64) * 8]), 16, 0, 0);\
    }                                                                                             \
  }

  STAGE(0, 0);
  __syncthreads();

  for (int s = 0; s < 33; ++s) {
    int nb = s & 1;
    if (s + 1 < 33) {
      int nk = (s + 1 <= qtA) ? (s + 1) : (s + 1 - (qtA + 1));
      STAGE(nk, nb ^ 1);
    }
    int kt = (s <= qtA) ? s : (s - (qtA + 1));
    bool diag = (s == qtA) || (s == 32);
    int qrow0 = qt * 64 + wave * 16 + lg * 4;

    f32x4 sc[4];
#pragma unroll
    for (int cb = 0; cb < 4; cb++) sc[cb] = (f32x4){0.f, 0.f, 0.f, 0.f};
    __builtin_amdgcn_s_setprio(1);
#pragma unroll
    for (int kk = 0; kk < 4; kk++) {
#pragma unroll
      for (int cb = 0; cb < 4; cb++) {
        bf16x8 kf = *(const bf16x8*)&Ks[nb][(cb * 16 + l15) * 128 + ((kk * 32 + lg * 8) ^ sw)];
        sc[cb] = MFMA16(qf[kk], kf, sc[cb]);
      }
    }
    __builtin_amdgcn_s_setprio(0);
    if (diag) {
#pragma unroll
      for (int cb = 0; cb < 4; cb++) {
        int col = kt * 64 + cb * 16 + l15;
#pragma unroll
        for (int j = 0; j < 4; j++) {
          float v = sc[cb][j] * kscale;
          if (col > qrow0 + j) v = -INFINITY;
          sc[cb][j] = v;
        }
      }
    } else {
#pragma unroll
      for (int cb = 0; cb < 4; cb++)
#pragma unroll
        for (int j = 0; j < 4; j++) sc[cb][j] *= kscale;
    }
    float pm[4];
#pragma unroll
    for (int j = 0; j < 4; j++)
      pm[j] = fmaxf(fmaxf(sc[0][j], sc[1][j]), fmaxf(sc[2][j], sc[3][j]));
    bool grow = !__all((pm[0] <= m_r[0] + THR) & (pm[1] <= m_r[1] + THR) &
                       (pm[2] <= m_r[2] + THR) & (pm[3] <= m_r[3] + THR));
    if (grow) {
#pragma unroll
      for (int off = 1; off < 16; off <<= 1) {
#pragma unroll
        for (int j = 0; j < 4; j++) pm[j] = fmaxf(pm[j], __shfl_xor(pm[j], off));
      }
#pragma unroll
      for (int j = 0; j < 4; j++) {
        float mn = fmaxf(m_r[j], pm[j]);
        float corr = fast_exp2(m_r[j] - mn);
        m_r[j] = mn;
        l_r[j] *= corr;
#pragma unroll
        for (int db = 0; db < 8; db++) oacc[db][j] *= corr;
      }
    }
#pragma unroll
    for (int cb = 0; cb < 4; cb++)
#pragma unroll
      for (int j = 0; j < 4; j++)
        Ps[wave][(lg * 4 + j) * 80 + cb * 16 + l15] = f2bf(fast_exp2(sc[cb][j] - m_r[j]));
    f32x4 sacc = (f32x4){0.f, 0.f, 0.f, 0.f};
    __builtin_amdgcn_s_setprio(1);
#pragma unroll
    for (int kc = 0; kc < 2; kc++) {
      bf16x8 pa = *(const bf16x8*)&Ps[wave][l15 * 80 + kc * 32 + lg * 8];
      sacc = MFMA16(pa, ones, sacc);
#pragma unroll
      for (int db = 0; db < 8; db++) {
        bf16x8 vb = *(const bf16x8*)&VTs[nb][(db * 16 + l15) * 64 + ((kc * 32 + lg * 8) ^ sw)];
        oacc[db] = MFMA16(pa, vb, oacc[db]);
      }
    }
    __builtin_amdgcn_s_setprio(0);
#pragma unroll
    for (int j = 0; j < 4; j++) l_r[j] += sacc[j];
    __syncthreads();

    if (s == qtA) {
      int qrow_e = qt * 64 + wave * 16 + lg * 4;
#pragma unroll
      for (int db = 0; db < 8; db++) {
        int d = db * 16 + l15;
#pragma unroll
        for (int j = 0; j < 4; j++) {
          float val = oacc[db][j] / l_r[j];
          o[((size_t)(b * 2048 + qrow_e + j)) * 2048 + h * 128 + d] = f2bf(val);
        }
      }
      qt = qtB;
      LOAD_Q();
#pragma unroll
      for (int j = 0; j < 4; j++) { m_r[j] = -INFINITY; l_r[j] = 0.f; }
#pragma unroll
      for (int db = 0; db < 8; db++) oacc[db] = (f32x4){0.f, 0.f, 0.f, 0.f};
    }
  }
  int qrow_e = qt * 64 + wave * 16 + lg * 4;
#pragma unroll
  for (int db = 0; db < 8; db++) {
    int d = db * 16 + l15;
#pragma unroll
    for (int j = 0; j < 4; j++) {
      float val = oacc[db][j] / l_r[j];
      o[((size_t)(b * 2048 + qrow_e + j)) * 2048 + h * 128 + d] = f2bf(val);
    }
  }
#undef STAGE
#undef LOAD_Q
}

// ---------- host launch ----------
extern "C" void kernel_launch(void* const* d_in, const int* in_sizes, int n_in,
                              void* d_out, int out_size, void* d_ws, size_t ws_size,
                              hipStream_t stream) {
  (void)in_sizes; (void)n_in; (void)out_size; (void)ws_size;
  const float* x    = (const float*)d_in[0];
  const float* Wq   = (const float*)d_in[1];
  const float* Wkv  = (const float*)d_in[2];
  const float* Wkvh = (const float*)d_in[3];
  const float* Wg   = (const float*)d_in[4];
  const float* Wout = (const float*)d_in[5];
  float* out = (float*)d_out;

  char* ws = (char*)d_ws;
  size_t off = 0;
  auto alloc = [&](size_t bytes) -> void* {
    void* p = ws + off;
    off += (bytes + 255) & ~(size_t)255;
    return p;
  };
  unsigned short* x_bf    = (unsigned short*)alloc(4096ull * 2048 * 2);
  unsigned short* wq_bf   = (unsigned short*)alloc(2048ull * 2048 * 2);   // must stay adjacent to wsm_bf
  unsigned short* wsm_bf  = (unsigned short*)alloc(384ull * 2048 * 2);    // rows 2048..2431 of merged B
  unsigned short* wout_bf = (unsigned short*)alloc(2048ull * 2048 * 2);
  unsigned short* q_r     = (unsigned short*)alloc(4096ull * 2048 * 2);
  unsigned short* k_r     = (unsigned short*)alloc(4096ull * 2048 * 2);
  unsigned short* o_bf    = (unsigned short*)alloc(4096ull * 2048 * 2);
  float* small_out        = (float*)alloc(4096ull * 384 * 4);
  float* lsg_t            = (float*)alloc(64ull * 2048 * 4);
  float* khvh             = (float*)alloc(4096ull * 32 * 4);
  float2* cs              = (float2*)alloc(2048ull * 64 * 8);
  float* wgt              = (float*)alloc(2048ull * 32 * 4);
  unsigned short* v_t     = x_bf;  // x_bf dead after merged GEMM

  prep<<<9344, 256, 0, stream>>>(x, Wq, Wout, Wkv, Wkvh, Wg, x_bf, wq_bf, wout_bf, wsm_bf, cs, wgt);
  gproj<<<512, 256, 0, stream>>>(x, wgt, lsg_t);
  gemm_bt<1><<<dim3(19, 32), 256, 0, stream>>>(x_bf, wq_bf, small_out, q_r, 2048, 384);
  scan_kernel<<<64, 256, 0, stream>>>(lsg_t, small_out, khvh);
  build_kv2<<<dim3(32, 32), 256, 0, stream>>>(small_out, khvh, cs, k_r, v_t);
  flash_attn<<<dim3(16, 32), 256, 0, stream>>>(q_r, k_r, v_t, cs, o_bf);
  gemm_bt<0><<<dim3(16, 32), 256, 0, stream>>>(o_bf, wout_bf, out, nullptr, 2048, 2048);
}

// Round 9
// 284.049 us; speedup vs baseline: 1.9174x; 1.0629x over previous
//
#include <hip/hip_runtime.h>
#include <hip/hip_bf16.h>
#include <math.h>

// ---------- types ----------
typedef __attribute__((ext_vector_type(8))) short bf16x8;
typedef __attribute__((ext_vector_type(4))) float f32x4;

#define MFMA16(a, b, c) __builtin_amdgcn_mfma_f32_16x16x32_bf16((a), (b), (c), 0, 0, 0)

static __device__ __forceinline__ float fast_exp2(float x) { return __builtin_amdgcn_exp2f(x); }

static __device__ __forceinline__ unsigned short f2bf(float f) {
  __hip_bfloat16 h = __float2bfloat16(f);
  unsigned short u;
  __builtin_memcpy(&u, &h, 2);
  return u;
}
static __device__ __forceinline__ float bf2f(unsigned short u) {
  unsigned int x = ((unsigned int)u) << 16;
  float f;
  __builtin_memcpy(&f, &x, 4);
  return f;
}

// ---------- merged prep: casts + wsmall + rope table + wg transpose ----------
static __device__ __forceinline__ void cast8(const float* __restrict__ src,
                                             unsigned short* __restrict__ dst, int blk, int tid) {
  int i = (blk * 256 + tid) * 8;
  float4 a = *(const float4*)(src + i);
  float4 b = *(const float4*)(src + i + 4);
  union { unsigned short u[8]; bf16x8 v; } o;
  o.u[0] = f2bf(a.x); o.u[1] = f2bf(a.y); o.u[2] = f2bf(a.z); o.u[3] = f2bf(a.w);
  o.u[4] = f2bf(b.x); o.u[5] = f2bf(b.y); o.u[6] = f2bf(b.z); o.u[7] = f2bf(b.w);
  *(bf16x8*)(dst + i) = o.v;
}

__global__ __launch_bounds__(256) void prep(const float* __restrict__ x, const float* __restrict__ Wq,
                                            const float* __restrict__ Wout, const float* __restrict__ Wkv,
                                            const float* __restrict__ Wkvh, const float* __restrict__ Wg,
                                            unsigned short* __restrict__ x_bf, unsigned short* __restrict__ wq_bf,
                                            unsigned short* __restrict__ wout_bf, unsigned short* __restrict__ wsm_bf,
                                            float2* __restrict__ cs, float* __restrict__ wgt) {
  int bid = blockIdx.x, tid = threadIdx.x;
  if (bid < 4096) {
    cast8(x, x_bf, bid, tid);
  } else if (bid < 6144) {
    cast8(Wq, wq_bf, bid - 4096, tid);
  } else if (bid < 8192) {
    cast8(Wout, wout_bf, bid - 6144, tid);
  } else if (bid < 8576) {
    int row = bid - 8192;
    int c = tid * 8;
    const float* src = nullptr;
    if (row < 256) src = Wkv + (size_t)row * 2048;
    else if (row < 288) src = Wkvh + (size_t)(row - 256) * 2048;
    union { unsigned short u[8]; bf16x8 v; } o;
    if (src) {
      float4 a = *(const float4*)(src + c);
      float4 b = *(const float4*)(src + c + 4);
      o.u[0] = f2bf(a.x); o.u[1] = f2bf(a.y); o.u[2] = f2bf(a.z); o.u[3] = f2bf(a.w);
      o.u[4] = f2bf(b.x); o.u[5] = f2bf(b.y); o.u[6] = f2bf(b.z); o.u[7] = f2bf(b.w);
    } else {
      for (int j = 0; j < 8; j++) o.u[j] = 0;
    }
    *(bf16x8*)(wsm_bf + (size_t)row * 2048 + c) = o.v;
  } else if (bid < 9088) {
    int i = (bid - 8576) * 256 + tid;
    int f = i & 63, n = i >> 6;
    float inv = powf(10000.0f, -(float)(2 * f) / 128.0f);
    float ang = (float)n * inv;
    cs[i] = make_float2(cosf(ang), sinf(ang));
  } else {
    int i = (bid - 9088) * 256 + tid;
    int oc = i >> 11, k = i & 2047;
    wgt[(size_t)k * 32 + oc] = Wg[i];
  }
}

// ---------- lsg_t[b][ch][n] = log_sigmoid(x @ Wg^T), transposed write ----------
__global__ __launch_bounds__(256) void gproj(const float* __restrict__ x, const float* __restrict__ Wgt,
                                             float* __restrict__ lsg_t) {
  int tid = blockIdx.x * 256 + threadIdx.x;  // 4096*32
  int tok = tid >> 5, oc = tid & 31;
  const float* xr = x + (size_t)tok * 2048;
  float acc = 0.f;
  for (int k = 0; k < 2048; k += 4) {
    float4 a = *(const float4*)(xr + k);
    acc += a.x * Wgt[(size_t)k * 32 + oc] + a.y * Wgt[(size_t)(k + 1) * 32 + oc] +
           a.z * Wgt[(size_t)(k + 2) * 32 + oc] + a.w * Wgt[(size_t)(k + 3) * 32 + oc];
  }
  float ls = (acc >= 0.f) ? -log1pf(expf(-acc)) : acc - log1pf(expf(acc));
  int b = tok >> 11, n = tok & 2047;
  lsg_t[((size_t)(b * 32 + oc)) * 2048 + n] = ls;
}

// ---------- scan v3: 64 blocks (b,ch), 256 thr x 8 toks, shfl wave-scan ----------
__global__ __launch_bounds__(256) void scan_kernel(const float* __restrict__ lsg_t,
                                                   const float* __restrict__ so,
                                                   float* __restrict__ khvh) {
  int b = blockIdx.x >> 5, ch = blockIdx.x & 31;
  int t = threadIdx.x, lane = t & 63, wv = t >> 6;
  const float* L = lsg_t + ((size_t)(b * 32 + ch)) * 2048 + t * 8;
  float ls[8], v[8];
  float4 a = *(const float4*)L, c = *(const float4*)(L + 4);
  ls[0] = a.x; ls[1] = a.y; ls[2] = a.z; ls[3] = a.w;
  ls[4] = c.x; ls[5] = c.y; ls[6] = c.z; ls[7] = c.w;
  const float* V = so + ((size_t)(b * 2048 + t * 8)) * 384 + 256 + ch;
#pragma unroll
  for (int j = 0; j < 8; j++) v[j] = V[(size_t)j * 384];
  float run = 0.f;
#pragma unroll
  for (int j = 0; j < 8; j++) run += ls[j];
  float incl = run;
#pragma unroll
  for (int off = 1; off < 64; off <<= 1) {
    float nv = __shfl_up(incl, off);
    if (lane >= off) incl += nv;
  }
  __shared__ float ws[2][4];
  if (lane == 63) ws[0][wv] = incl;
  __syncthreads();
  float wbase = 0.f;
#pragma unroll
  for (int w = 0; w < 4; w++) wbase += (w < wv) ? ws[0][w] : 0.f;
  float baseA = wbase + incl - run;
  float lf = baseA, s = 0.f;
#pragma unroll
  for (int j = 0; j < 8; j++) { s += v[j] * __expf(lf); lf += ls[j]; }
  float incl2 = s;
#pragma unroll
  for (int off = 1; off < 64; off <<= 1) {
    float nv = __shfl_up(incl2, off);
    if (lane >= off) incl2 += nv;
  }
  if (lane == 63) ws[1][wv] = incl2;
  __syncthreads();
  float wbase2 = 0.f;
#pragma unroll
  for (int w = 0; w < 4; w++) wbase2 += (w < wv) ? ws[1][w] : 0.f;
  float base2 = wbase2 + incl2 - s;
  lf = baseA; s = base2;
  float* O = khvh + ((size_t)(b * 2048 + t * 8)) * 32 + ch;
#pragma unroll
  for (int j = 0; j < 8; j++) { s += v[j] * __expf(lf); lf += ls[j]; O[(size_t)j * 32] = s; }
}

// ---------- build_kv2: merged k_r build (+rope) and v_t transposed build ----------
__global__ __launch_bounds__(256) void build_kv2(const float* __restrict__ so,
                                                 const float* __restrict__ khvh,
                                                 const float2* __restrict__ cs,
                                                 unsigned short* __restrict__ k_r,
                                                 unsigned short* __restrict__ v_t) {
  int ntb = blockIdx.x, bh = blockIdx.y;
  int b = bh >> 4, h = bh & 15;
  int tok0 = b * 2048 + ntb * 64;
  int n0 = ntb * 64;
  __shared__ float khs[64], vhs[64];
  __shared__ unsigned short Vt_s[64 * 132];
  int t = threadIdx.x;
  if (t < 64) {
    khs[t] = khvh[(size_t)(tok0 + t) * 32 + h];
    vhs[t] = khvh[(size_t)(tok0 + t) * 32 + 16 + h];
  }
  __syncthreads();
#pragma unroll
  for (int c = 0; c < 4; c++) {
    int idx = c * 256 + t;
    int r = idx >> 4, q4 = (idx & 15) * 4;
    const float* sop = so + (size_t)(tok0 + r) * 384;
    float4 k1 = *(const float4*)(sop + q4);
    float4 k2 = *(const float4*)(sop + 64 + q4);
    float kh = khs[r];
    int n = n0 + r;
    union { unsigned short u[4]; uint2 v2; } o1, o2;
#pragma unroll
    for (int j = 0; j < 4; j++) {
      float2 cc = cs[(n << 6) + q4 + j];
      float av = ((const float*)&k1)[j], bv = ((const float*)&k2)[j];
      o1.u[j] = f2bf((av * cc.x - bv * cc.y) * kh);
      o2.u[j] = f2bf((bv * cc.x + av * cc.y) * kh);
    }
    size_t off = ((size_t)bh * 2048 + n) * 128 + q4;
    *(uint2*)(k_r + off) = o1.v2;
    *(uint2*)(k_r + off + 64) = o2.v2;
  }
#pragma unroll
  for (int c = 0; c < 8; c++) {
    int idx = c * 256 + t;
    int r = idx >> 5, d4 = (idx & 31) * 4;
    const float* sop = so + (size_t)(tok0 + r) * 384 + 128;
    float4 v = *(const float4*)(sop + d4);
    float vh = vhs[r];
    union { unsigned short u[4]; uint2 v2; } ov;
#pragma unroll
    for (int j = 0; j < 4; j++) ov.u[j] = f2bf(((const float*)&v)[j] * vh);
    *(uint2*)&Vt_s[r * 132 + d4] = ov.v2;
  }
  __syncthreads();
#pragma unroll
  for (int c = 0; c < 4; c++) {
    int idx = c * 256 + t;
    int d = idx >> 3, c8 = (idx & 7) * 8;
    union { unsigned short u[8]; bf16x8 v; } o;
#pragma unroll
    for (int j = 0; j < 8; j++) o.u[j] = Vt_s[(c8 + j) * 132 + d];
    *(bf16x8*)(v_t + ((size_t)bh * 128 + d) * 2048 + n0 + c8) = o.v;
  }
}

// ---------- m97-structure NT GEMM (verified 2-barrier, 16 KB LDS, XCD swizzle) ----------
// MODE 0: C fp32 (ldc).  MODE 1: merged q+small — cols<2048 scatter bf16 to q_r, cols>=2048 fp32 small_out.
template <int MODE>
__global__ __launch_bounds__(256) void gemm_bt(const unsigned short* __restrict__ A,
                                               const unsigned short* __restrict__ B,
                                               float* __restrict__ Cf,
                                               unsigned short* __restrict__ Cb,
                                               int K, int ldc) {
  __shared__ unsigned short As[128 * 32];
  __shared__ unsigned short Bs[128 * 32];
  int tid = threadIdx.x;
  int wave = tid >> 6, lane = tid & 63, l15 = lane & 15, lg = lane >> 4;
  int wr = wave >> 1, wc = wave & 1;
  int lin = blockIdx.y * gridDim.x + blockIdx.x;
  int cpx = (gridDim.x * gridDim.y) >> 3;
  int swz = (lin & 7) * cpx + (lin >> 3);
  int bx = swz % gridDim.x, by = swz / gridDim.x;
  int row0 = by * 128, col0 = bx * 128;
  f32x4 acc[4][4];
#pragma unroll
  for (int m = 0; m < 4; m++)
#pragma unroll
    for (int n = 0; n < 4; n++) acc[m][n] = (f32x4){0.f, 0.f, 0.f, 0.f};

  for (int k0 = 0; k0 < K; k0 += 32) {
#pragma unroll
    for (int c = 0; c < 2; c++) {
      int chunk = c * 256 + tid;
      int r = chunk >> 2, kk = (chunk & 3) * 8;
      __builtin_amdgcn_global_load_lds(
          (const __attribute__((address_space(1))) void*)(A + (size_t)(row0 + r) * K + k0 + kk),
          (__attribute__((address_space(3))) void*)(As + ((size_t)c * 256 + wave * 64) * 8), 16, 0, 0);
      __builtin_amdgcn_global_load_lds(
          (const __attribute__((address_space(1))) void*)(B + (size_t)(col0 + r) * K + k0 + kk),
          (__attribute__((address_space(3))) void*)(Bs + ((size_t)c * 256 + wave * 64) * 8), 16, 0, 0);
    }
    __syncthreads();
    bf16x8 af[4], bfr[4];
#pragma unroll
    for (int m = 0; m < 4; m++) af[m] = *(const bf16x8*)&As[(wr * 64 + m * 16 + l15) * 32 + lg * 8];
#pragma unroll
    for (int n = 0; n < 4; n++) bfr[n] = *(const bf16x8*)&Bs[(wc * 64 + n * 16 + l15) * 32 + lg * 8];
#pragma unroll
    for (int m = 0; m < 4; m++)
#pragma unroll
      for (int n = 0; n < 4; n++) acc[m][n] = MFMA16(af[m], bfr[n], acc[m][n]);
    __syncthreads();
  }

  if (MODE == 0 || col0 >= 2048) {
#pragma unroll
    for (int m = 0; m < 4; m++) {
      int row_b = row0 + wr * 64 + m * 16 + lg * 4;
#pragma unroll
      for (int n = 0; n < 4; n++) {
        int col = col0 + wc * 64 + n * 16 + l15;
        int cw = (MODE == 0) ? col : (col - 2048);
#pragma unroll
        for (int j = 0; j < 4; j++) {
          Cf[(size_t)(row_b + j) * ldc + cw] = acc[m][n][j];
        }
      }
    }
  } else {
#pragma unroll
    for (int m = 0; m < 4; m++) {
      int row_b = row0 + wr * 64 + m * 16 + lg * 4;
#pragma unroll
      for (int n = 0; n < 4; n++) {
        int col = col0 + wc * 64 + n * 16 + l15;
        int h = col >> 7, d = col & 127;
#pragma unroll
        for (int j = 0; j < 4; j++) {
          int row = row_b + j;
          int b = row >> 11, nn = row & 2047;
          Cb[(((size_t)b * 16 + h) * 2048 + nn) * 128 + d] = f2bf(acc[m][n][j]);
        }
      }
    }
  }
}

// ---------- flash attention v4.1 (unchanged) ----------
__global__ __launch_bounds__(256, 2) void flash_attn(const unsigned short* __restrict__ q_r,
                                                     const unsigned short* __restrict__ k_r,
                                                     const unsigned short* __restrict__ v_t,
                                                     const float2* __restrict__ cs,
                                                     unsigned short* __restrict__ o) {
  int lin = blockIdx.y * 16 + blockIdx.x;
  int swz = (lin & 7) * 64 + (lin >> 3);
  int bx = swz & 15, bh = swz >> 4;
  const unsigned short* Kg = k_r + (size_t)bh * 2048 * 128;
  const unsigned short* Vtg = v_t + (size_t)bh * 128 * 2048;
  __shared__ unsigned short Ks[2][64 * 128];
  __shared__ unsigned short VTs[2][128 * 64];
  __shared__ unsigned short Ps[4][16 * 80];
  int tid = threadIdx.x, wave = tid >> 6, lane = tid & 63, l15 = lane & 15, lg = lane >> 4;
  int sw = (l15 & 7) * 8;
  int b = bh >> 4, h = bh & 15;

  union { unsigned short u[8]; bf16x8 v; } onesu;
#pragma unroll
  for (int j = 0; j < 8; j++) onesu.u[j] = 0x3F80;
  const bf16x8 ones = onesu.v;

  int qtA = bx, qtB = 31 - bx;
  int qt = qtA;

  bf16x8 qf[4];
#define LOAD_Q()                                                                                   \
  {                                                                                                \
    const unsigned short* Qg = q_r + ((size_t)bh * 2048 + qt * 64) * 128;                          \
    int n = qt * 64 + wave * 16 + l15;                                                             \
    union { unsigned short u[8]; bf16x8 v; } r0, r1, r2, r3;                                       \
    r0.v = *(const bf16x8*)(Qg + (wave * 16 + l15) * 128 + 0 * 32 + lg * 8);                       \
    r1.v = *(const bf16x8*)(Qg + (wave * 16 + l15) * 128 + 1 * 32 + lg * 8);                       \
    r2.v = *(const bf16x8*)(Qg + (wave * 16 + l15) * 128 + 2 * 32 + lg * 8);                       \
    r3.v = *(const bf16x8*)(Qg + (wave * 16 + l15) * 128 + 3 * 32 + lg * 8);                       \
    union { unsigned short u[8]; bf16x8 v; } o0, o1, o2, o3;                                       \
    _Pragma("unroll") for (int j = 0; j < 8; j++) {                                                \
      float2 c0 = cs[(n << 6) + 0 * 32 + lg * 8 + j];                                              \
      float t1 = bf2f(r0.u[j]), t2 = bf2f(r2.u[j]);                                                \
      o0.u[j] = f2bf(t1 * c0.x - t2 * c0.y);                                                       \
      o2.u[j] = f2bf(t2 * c0.x + t1 * c0.y);                                                       \
      float2 c1 = cs[(n << 6) + 1 * 32 + lg * 8 + j];                                              \
      float s1 = bf2f(r1.u[j]), s2 = bf2f(r3.u[j]);                                                \
      o1.u[j] = f2bf(s1 * c1.x - s2 * c1.y);                                                       \
      o3.u[j] = f2bf(s2 * c1.x + s1 * c1.y);                                                       \
    }                                                                                              \
    qf[0] = o0.v; qf[1] = o1.v; qf[2] = o2.v; qf[3] = o3.v;                                        \
  }

  LOAD_Q();

  float m_r[4], l_r[4];
  f32x4 oacc[8];
#pragma unroll
  for (int j = 0; j < 4; j++) { m_r[j] = -INFINITY; l_r[j] = 0.f; }
#pragma unroll
  for (int db = 0; db < 8; db++) oacc[db] = (f32x4){0.f, 0.f, 0.f, 0.f};

  const float kscale = 0.12753102f;  // (1/sqrt(128)) * log2(e)
  const float THR = 11.0f;

#define STAGE(kt, bsel)                                                                           \
  {                                                                                               \
    int kti = (kt);                                                                               \
    int bs = (bsel);                                                                              \
    _Pragma("unroll") for (int c = 0; c < 4; c++) {                                               \
      int s = c * 256 + tid;                                                                      \
      int kr = s >> 4, kc = ((s & 15) ^ (kr & 7)) * 8;                                            \
      __builtin_amdgcn_global_load_lds(                                                           \
          (const __attribute__((address_space(1))) void*)(Kg + (size_t)(kti * 64 + kr) * 128 + kc),\
          (__attribute__((address_space(3))) void*)(&Ks[bs][(c * 256 + wave * 64) * 8]), 16, 0, 0);\
      int vr = s >> 3, vc = ((s & 7) ^ (vr & 7)) * 8;                                             \
      __builtin_amdgcn_global_load_lds(                                                           \
          (const __attribute__((address_space(1))) void*)(Vtg + (size_t)vr * 2048 + kti * 64 + vc),\
          (__attribute__((address_space(3))) void*)(&VTs[bs][(c * 256 + wave * 64) * 8]), 16, 0, 0);\
    }                                                                                             \
  }

  STAGE(0, 0);
  __syncthreads();

  for (int s = 0; s < 33; ++s) {
    int nb = s & 1;
    if (s + 1 < 33) {
      int nk = (s + 1 <= qtA) ? (s + 1) : (s + 1 - (qtA + 1));
      STAGE(nk, nb ^ 1);
    }
    int kt = (s <= qtA) ? s : (s - (qtA + 1));
    bool diag = (s == qtA) || (s == 32);
    int qrow0 = qt * 64 + wave * 16 + lg * 4;

    f32x4 sc[4];
#pragma unroll
    for (int cb = 0; cb < 4; cb++) sc[cb] = (f32x4){0.f, 0.f, 0.f, 0.f};
    __builtin_amdgcn_s_setprio(1);
#pragma unroll
    for (int kk = 0; kk < 4; kk++) {
#pragma unroll
      for (int cb = 0; cb < 4; cb++) {
        bf16x8 kf = *(const bf16x8*)&Ks[nb][(cb * 16 + l15) * 128 + ((kk * 32 + lg * 8) ^ sw)];
        sc[cb] = MFMA16(qf[kk], kf, sc[cb]);
      }
    }
    __builtin_amdgcn_s_setprio(0);
    if (diag) {
#pragma unroll
      for (int cb = 0; cb < 4; cb++) {
        int col = kt * 64 + cb * 16 + l15;
#pragma unroll
        for (int j = 0; j < 4; j++) {
          float v = sc[cb][j] * kscale;
          if (col > qrow0 + j) v = -INFINITY;
          sc[cb][j] = v;
        }
      }
    } else {
#pragma unroll
      for (int cb = 0; cb < 4; cb++)
#pragma unroll
        for (int j = 0; j < 4; j++) sc[cb][j] *= kscale;
    }
    float pm[4];
#pragma unroll
    for (int j = 0; j < 4; j++)
      pm[j] = fmaxf(fmaxf(sc[0][j], sc[1][j]), fmaxf(sc[2][j], sc[3][j]));
    bool grow = !__all((pm[0] <= m_r[0] + THR) & (pm[1] <= m_r[1] + THR) &
                       (pm[2] <= m_r[2] + THR) & (pm[3] <= m_r[3] + THR));
    if (grow) {
#pragma unroll
      for (int off = 1; off < 16; off <<= 1) {
#pragma unroll
        for (int j = 0; j < 4; j++) pm[j] = fmaxf(pm[j], __shfl_xor(pm[j], off));
      }
#pragma unroll
      for (int j = 0; j < 4; j++) {
        float mn = fmaxf(m_r[j], pm[j]);
        float corr = fast_exp2(m_r[j] - mn);
        m_r[j] = mn;
        l_r[j] *= corr;
#pragma unroll
        for (int db = 0; db < 8; db++) oacc[db][j] *= corr;
      }
    }
#pragma unroll
    for (int cb = 0; cb < 4; cb++)
#pragma unroll
      for (int j = 0; j < 4; j++)
        Ps[wave][(lg * 4 + j) * 80 + cb * 16 + l15] = f2bf(fast_exp2(sc[cb][j] - m_r[j]));
    f32x4 sacc = (f32x4){0.f, 0.f, 0.f, 0.f};
    __builtin_amdgcn_s_setprio(1);
#pragma unroll
    for (int kc = 0; kc < 2; kc++) {
      bf16x8 pa = *(const bf16x8*)&Ps[wave][l15 * 80 + kc * 32 + lg * 8];
      sacc = MFMA16(pa, ones, sacc);
#pragma unroll
      for (int db = 0; db < 8; db++) {
        bf16x8 vb = *(const bf16x8*)&VTs[nb][(db * 16 + l15) * 64 + ((kc * 32 + lg * 8) ^ sw)];
        oacc[db] = MFMA16(pa, vb, oacc[db]);
      }
    }
    __builtin_amdgcn_s_setprio(0);
#pragma unroll
    for (int j = 0; j < 4; j++) l_r[j] += sacc[j];
    __syncthreads();

    if (s == qtA) {
      int qrow_e = qt * 64 + wave * 16 + lg * 4;
#pragma unroll
      for (int db = 0; db < 8; db++) {
        int d = db * 16 + l15;
#pragma unroll
        for (int j = 0; j < 4; j++) {
          float val = oacc[db][j] / l_r[j];
          o[((size_t)(b * 2048 + qrow_e + j)) * 2048 + h * 128 + d] = f2bf(val);
        }
      }
      qt = qtB;
      LOAD_Q();
#pragma unroll
      for (int j = 0; j < 4; j++) { m_r[j] = -INFINITY; l_r[j] = 0.f; }
#pragma unroll
      for (int db = 0; db < 8; db++) oacc[db] = (f32x4){0.f, 0.f, 0.f, 0.f};
    }
  }
  int qrow_e = qt * 64 + wave * 16 + lg * 4;
#pragma unroll
  for (int db = 0; db < 8; db++) {
    int d = db * 16 + l15;
#pragma unroll
    for (int j = 0; j < 4; j++) {
      float val = oacc[db][j] / l_r[j];
      o[((size_t)(b * 2048 + qrow_e + j)) * 2048 + h * 128 + d] = f2bf(val);
    }
  }
#undef STAGE
#undef LOAD_Q
}

// ---------- host launch ----------
extern "C" void kernel_launch(void* const* d_in, const int* in_sizes, int n_in,
                              void* d_out, int out_size, void* d_ws, size_t ws_size,
                              hipStream_t stream) {
  (void)in_sizes; (void)n_in; (void)out_size; (void)ws_size;
  const float* x    = (const float*)d_in[0];
  const float* Wq   = (const float*)d_in[1];
  const float* Wkv  = (const float*)d_in[2];
  const float* Wkvh = (const float*)d_in[3];
  const float* Wg   = (const float*)d_in[4];
  const float* Wout = (const float*)d_in[5];
  float* out = (float*)d_out;

  char* ws = (char*)d_ws;
  size_t off = 0;
  auto alloc = [&](size_t bytes) -> void* {
    void* p = ws + off;
    off += (bytes + 255) & ~(size_t)255;
    return p;
  };
  unsigned short* x_bf    = (unsigned short*)alloc(4096ull * 2048 * 2);
  unsigned short* wq_bf   = (unsigned short*)alloc(2048ull * 2048 * 2);   // must stay adjacent to wsm_bf
  unsigned short* wsm_bf  = (unsigned short*)alloc(384ull * 2048 * 2);    // rows 2048..2431 of merged B
  unsigned short* wout_bf = (unsigned short*)alloc(2048ull * 2048 * 2);
  unsigned short* q_r     = (unsigned short*)alloc(4096ull * 2048 * 2);
  unsigned short* k_r     = (unsigned short*)alloc(4096ull * 2048 * 2);
  unsigned short* o_bf    = (unsigned short*)alloc(4096ull * 2048 * 2);
  float* small_out        = (float*)alloc(4096ull * 384 * 4);
  float* lsg_t            = (float*)alloc(64ull * 2048 * 4);
  float* khvh             = (float*)alloc(4096ull * 32 * 4);
  float2* cs              = (float2*)alloc(2048ull * 64 * 8);
  float* wgt              = (float*)alloc(2048ull * 32 * 4);
  unsigned short* v_t     = x_bf;  // x_bf dead after merged GEMM

  prep<<<9344, 256, 0, stream>>>(x, Wq, Wout, Wkv, Wkvh, Wg, x_bf, wq_bf, wout_bf, wsm_bf, cs, wgt);
  gproj<<<512, 256, 0, stream>>>(x, wgt, lsg_t);
  gemm_bt<1><<<dim3(19, 32), 256, 0, stream>>>(x_bf, wq_bf, small_out, q_r, 2048, 384);
  scan_kernel<<<64, 256, 0, stream>>>(lsg_t, small_out, khvh);
  build_kv2<<<dim3(32, 32), 256, 0, stream>>>(small_out, khvh, cs, k_r, v_t);
  flash_attn<<<dim3(16, 32), 256, 0, stream>>>(q_r, k_r, v_t, cs, o_bf);
  gemm_bt<0><<<dim3(16, 32), 256, 0, stream>>>(o_bf, wout_bf, out, nullptr, 2048, 2048);
}